// Round 1
// 458.392 us; speedup vs baseline: 1.1238x; 1.1238x over previous
//
#include <hip/hip_runtime.h>
#include <hip/hip_bf16.h>

typedef __hip_bfloat16 bf16;
typedef __attribute__((ext_vector_type(8))) short short8;   // 8 bf16 (4 VGPRs)
typedef __attribute__((ext_vector_type(4))) float f32x4;    // 4 fp32 acc
typedef __attribute__((ext_vector_type(2))) float f32x2;
typedef _Float16 h2 __attribute__((ext_vector_type(2)));    // packed half2

constexpr int NN = 50000;   // nodes
constexpr int NE = 800000;  // edges
constexpr int IC = 64;      // in channels
constexpr int OC = 128;     // out channels
constexpr int NH = 4;       // heads
constexpr unsigned F32_ONE = 0x3F800000u;
// 1/sqrt(32) * log2(e): exp(l) = exp2(l*log2e), constants fused
constexpr float KC = 0.25503486f;

__device__ __forceinline__ float ldf(const void* p, int i, bool f32) {
    return f32 ? ((const float*)p)[i]
               : __bfloat162float(((const bf16*)p)[i]);
}

__device__ __forceinline__ int ld_idx(const void* p, long long i, bool i64) {
    return i64 ? (int)((const long long*)p)[i] : ((const int*)p)[i];
}

__device__ __forceinline__ bool probe_i64(const void* ei) {
    const unsigned* u = (const unsigned*)ei;
    return (u[1] | u[3] | u[5] | u[7]) == 0u;
}

// f32 -> bf16 bits (RNE)
__device__ __forceinline__ unsigned f2bu(float x) {
    unsigned u = __float_as_uint(x);
    return (u + 0x7FFFu + ((u >> 16) & 1u)) >> 16;
}

__device__ __forceinline__ h2 u2h(unsigned u) { return __builtin_bit_cast(h2, u); }

// dot2: c += a[0]*b[0] + a[1]*b[1] (f16 inputs, f32 accum)
__device__ __forceinline__ float fdot2(h2 a, h2 b, float c) {
#if __has_builtin(__builtin_amdgcn_fdot2)
    return __builtin_amdgcn_fdot2(a, b, c, false);
#else
    return c + (float)a[0] * (float)b[0] + (float)a[1] * (float)b[1];
#endif
}

__device__ __forceinline__ h2 relu2(h2 a) {
    h2 z = {(_Float16)0.f, (_Float16)0.f};
#if __has_builtin(__builtin_elementwise_max)
    return __builtin_elementwise_max(a, z);
#else
    h2 r;
    r[0] = a[0] > (_Float16)0.f ? a[0] : (_Float16)0.f;
    r[1] = a[1] > (_Float16)0.f ? a[1] : (_Float16)0.f;
    return r;
#endif
}

// DPP-based add of a lane-permuted copy (VALU pipe; NO ds_bpermute).
// ctrl: 0xB1 = quad_perm xor1, 0x4E = quad_perm xor2,
//       0x128 = row_ror:8 (== xor8 within 16-row), 0x124 = row_ror:4.
// Sequence xor1,xor2,ror8,ror4 = full 16-lane allreduce (all lanes get sum).
#define DPPADD(x, ctrl) \
    ((x) + __int_as_float(__builtin_amdgcn_mov_dpp(__float_as_int(x), (ctrl), 0xF, 0xF, false)))

// ---- fp8 e4m3 helpers ------------------------------------------------------
__device__ __forceinline__ unsigned char f32_to_fp8(float x) {
#if __has_builtin(__builtin_amdgcn_cvt_pk_fp8_f32)
    return (unsigned char)(__builtin_amdgcn_cvt_pk_fp8_f32(x, x, 0, false) & 0xFF);
#else
    unsigned bits = __float_as_uint(x);
    unsigned s = bits >> 31;
    float a = fabsf(x);
    if (a >= 448.f) return (unsigned char)((s << 7) | 0x7E);
    if (a < 0.015625f) {
        int m = (int)(a * 512.f + 0.5f);
        if (m >= 8) return (unsigned char)((s << 7) | 0x08);
        return (unsigned char)((s << 7) | m);
    }
    unsigned ab = (bits & 0x7FFFFFFFu) + 0x00080000u;
    int e8 = (int)(ab >> 23) - 127 + 7;
    unsigned m3 = (ab >> 20) & 7u;
    if (e8 >= 16) return (unsigned char)((s << 7) | 0x7E);
    return (unsigned char)((s << 7) | ((unsigned)e8 << 3) | m3);
#endif
}

__device__ __forceinline__ void fp8x2_to_f32(unsigned u, float& f0, float& f1) {
#if __has_builtin(__builtin_amdgcn_cvt_pk_f32_fp8)
    f32x2 lo = __builtin_amdgcn_cvt_pk_f32_fp8(u, false);
    f0 = lo[0]; f1 = lo[1];
#else
    float r[2];
#pragma unroll
    for (int j = 0; j < 2; ++j) {
        unsigned b = (u >> (8 * j)) & 0xFF;
        unsigned s = b >> 7, e = (b >> 3) & 15, m = b & 7;
        float v = (e == 0) ? (float)m * 0.001953125f
                           : __uint_as_float(((e + 120u) << 23) | (m << 20));
        r[j] = s ? -v : v;
    }
    f0 = r[0]; f1 = r[1];
#endif
}

// ---------------------------------------------------------------------------
// prep: fused one-shot conversions + csr_count. (cnt/ssum zeroed by memset)
// bcat: [0,128)=bq, [128,256)=bk, [256,384)=bv, [384,512)=0 (a), [512,640)=be1 (b')
// We2h packing (for edge_gather's 16-lane scheme): entry t = lane*4 + k,
//   lane: g = lane>>4 (head), i = lane&15; pair index pp = 4*i + k;
//   value = half2( We2[2pp][g], We2[2pp+1][g] ).
// ---------------------------------------------------------------------------
constexpr int PB_X   = 12500;
constexpr int PB_W   = 160;
constexpr int PB_WO  = 64;
constexpr int PB_CNT = 3125;   // csr_count: NE/256

__global__ __launch_bounds__(256) void prep(
    const void* __restrict__ x,
    const void* __restrict__ Wq, const void* __restrict__ bq,
    const void* __restrict__ Wk, const void* __restrict__ bk,
    const void* __restrict__ Wv, const void* __restrict__ bv,
    const void* __restrict__ We1, const void* __restrict__ be1,
    const void* __restrict__ We2, const void* __restrict__ be2,
    const void* __restrict__ Wo,  const unsigned* __restrict__ gw,
    const void* __restrict__ eia, const void* __restrict__ eib, int split,
    bf16* __restrict__ xb, bf16* __restrict__ WcatT, bf16* __restrict__ WoT,
    int* __restrict__ cnt,
    unsigned* __restrict__ We2h, float* __restrict__ be2f,
    float* __restrict__ bcat)
{
    const bool f32 = (gw[0] == F32_ONE);
    int b = blockIdx.x, t = threadIdx.x;
    if (b < PB_X) {
        int i = b * 256 + t;
        if (i < NN * IC) xb[i] = __float2bfloat16(ldf(x, i, f32));
    } else if (b < PB_X + PB_W) {
        int idx = (b - PB_X) * 256 + t;         // n*64 + k
        int n = idx >> 6, k = idx & 63;
        int sel = n >> 7, c = n & 127;
        float v;
        if (sel == 0)      v = ldf(Wq, k * OC + c, f32);
        else if (sel == 1) v = ldf(Wk, k * OC + c, f32);
        else if (sel == 2) v = ldf(Wv, k * OC + c, f32);
        else if (sel == 3) v = ldf(We1, k * OC + c, f32);
        else               v = ldf(We1, (IC + k) * OC + c, f32);
        WcatT[idx] = __float2bfloat16(v);
    } else if (b < PB_X + PB_W + PB_WO) {
        int idx = (b - PB_X - PB_W) * 256 + t;  // n*128 + k
        int n = idx >> 7, k = idx & 127;
        WoT[idx] = __float2bfloat16(ldf(Wo, k * OC + n, f32));
    } else if (b < PB_X + PB_W + PB_WO + PB_CNT) {
        const bool i64 = probe_i64(eia);
        long long e = (long long)(b - PB_X - PB_W - PB_WO) * 256 + t;
        int d = split ? ld_idx(eib, e, i64) : ld_idx(eia, NE + e, i64);
        atomicAdd(&cnt[d], 1);
    } else {
        if (t < NH) be2f[t] = ldf(be2, t, f32);
        // We2h: 64 lanes x 4 dwords, per-lane 8-channel weight slice for ONE head
        {
            int ln = t >> 2, k = t & 3;         // t in [0,256)
            int g = ln >> 4, ii = ln & 15;
            int pp = 4 * ii + k;
            h2 hv;
            hv[0] = (_Float16)ldf(We2, (2 * pp) * NH + g, f32);
            hv[1] = (_Float16)ldf(We2, (2 * pp + 1) * NH + g, f32);
            We2h[t] = __builtin_bit_cast(unsigned, hv);
        }
        for (int n = t; n < 5 * OC; n += 256) {
            int sel = n >> 7, c = n & 127;
            float bb = 0.f;
            if (sel == 0) bb = ldf(bq, c, f32);
            else if (sel == 1) bb = ldf(bk, c, f32);
            else if (sel == 2) bb = ldf(bv, c, f32);
            else if (sel == 4) bb = ldf(be1, c, f32);  // fold be1 into b'
            bcat[n] = bb;
        }
    }
}

// ---------------------------------------------------------------------------
// csr_scan: exclusive prefix over cnt -> rowptr, cursor
// ---------------------------------------------------------------------------
__global__ __launch_bounds__(1024) void csr_scan(const int* __restrict__ cnt,
                                                 int* __restrict__ rowptr,
                                                 int* __restrict__ cursor)
{
    constexpr int T = 1024;
    constexpr int PER = (NN + T - 1) / T;
    __shared__ int psum[T];
    int t = threadIdx.x;
    int base = t * PER;
    int local = 0;
    for (int j = 0; j < PER; ++j) {
        int idx = base + j;
        if (idx < NN) local += cnt[idx];
    }
    psum[t] = local;
    __syncthreads();
    for (int off = 1; off < T; off <<= 1) {
        int v = (t >= off) ? psum[t - off] : 0;
        __syncthreads();
        psum[t] += v;
        __syncthreads();
    }
    int run = (t == 0) ? 0 : psum[t - 1];
    for (int j = 0; j < PER; ++j) {
        int idx = base + j;
        if (idx < NN) {
            rowptr[idx] = run;
            cursor[idx] = run;
            run += cnt[idx];
        }
    }
    if (t == T - 1) rowptr[NN] = run;
}

// ---------------------------------------------------------------------------
// node_gemm (+fused csr_fill): blocks [0,3125) GEMM, [3125,6250) fill.
// GEMM: D[50000 x 640] = xb @ Wcat + bcat (MFMA).
// Outputs: qb_dst row (f16, 512B) = [q 128ch | b' 128ch];
//          ka_src row (f16, 512B) = [k 128ch | a 128ch]; vf8 row 128B (fp8).
// ---------------------------------------------------------------------------
constexpr int NG_GEMM = 3125;   // NN/16
constexpr int NG_FILL = 3125;   // NE/256

__global__ __launch_bounds__(256) void node_gemm(
    const bf16* __restrict__ xb, const bf16* __restrict__ WcatT,
    const float* __restrict__ bcat,
    unsigned char* __restrict__ qb_dst, unsigned char* __restrict__ ka_src,
    unsigned char* __restrict__ vf8,
    const void* __restrict__ eia, const void* __restrict__ eib, int split,
    int* __restrict__ cursor, int* __restrict__ ssrc)
{
    if (blockIdx.x >= NG_GEMM) {
        // ---- csr_fill ----
        const bool i64 = probe_i64(eia);
        long long e = (long long)(blockIdx.x - NG_GEMM) * 256 + threadIdx.x;
        int s = ld_idx(eia, e, i64);
        int d = split ? ld_idx(eib, e, i64) : ld_idx(eia, NE + e, i64);
        int pos = atomicAdd(&cursor[d], 1);
        ssrc[pos] = s;
        return;
    }
    int wave = threadIdx.x >> 6;
    int lane = threadIdx.x & 63;
    int quad = lane >> 4;
    int l16  = lane & 15;
    int row_base = blockIdx.x * 16;
    int m = row_base + l16;

    short8 a0 = *(const short8*)(xb + (size_t)m * IC + quad * 8);
    short8 a1 = *(const short8*)(xb + (size_t)m * IC + 32 + quad * 8);

    _Float16* qh = (_Float16*)qb_dst;
    _Float16* kh = (_Float16*)ka_src;

#pragma unroll
    for (int t = 0; t < 10; ++t) {
        int colbase = wave * 160 + t * 16;
        const bf16* bp = WcatT + (size_t)(colbase + l16) * IC + quad * 8;
        short8 b0 = *(const short8*)(bp);
        short8 b1 = *(const short8*)(bp + 32);
        f32x4 acc = {0.f, 0.f, 0.f, 0.f};
        acc = __builtin_amdgcn_mfma_f32_16x16x32_bf16(a0, b0, acc, 0, 0, 0);
        acc = __builtin_amdgcn_mfma_f32_16x16x32_bf16(a1, b1, acc, 0, 0, 0);

        float bias = bcat[colbase + l16];
        int sel = colbase >> 7;
        int cc  = (colbase & 127) + l16;
#pragma unroll
        for (int r = 0; r < 4; ++r) {
            int node = row_base + quad * 4 + r;
            float fv = acc[r] + bias;
            if (sel == 2) {
                vf8[(size_t)node * OC + cc] = f32_to_fp8(fv);
            } else {
                _Float16 val = (_Float16)fv;
                if (sel == 0)      qh[(size_t)node * 256 + cc] = val;
                else if (sel == 1) kh[(size_t)node * 256 + cc] = val;
                else if (sel == 3) kh[(size_t)node * 256 + 128 + cc] = val;
                else               qh[(size_t)node * 256 + 128 + cc] = val;
            }
        }
    }
}

// ---------------------------------------------------------------------------
// edge_gather: FUSED edge logit + softmax-weighted aggregation, 2-edge ILP.
// 16-lane-partition scheme (zero LDS-pipe ops):
//   lane l: head g = l>>4, i = l&15.
//   t-partial: q/k channels {2l, 2l+1}  (dword at byte 4l of the 256B half)
//   p-partial: gate channels [8i, 8i+8) for head g (uint4 of a/b' + uint4 We2h)
//   Both reduced with a 4-step DPP allreduce confined to each 16-lane row
//   (quad_perm xor1, xor2, row_ror:8, row_ror:4) -> every lane holds t_g, p_g
//   for its own head g == l>>4, which is exactly the head of its v channels
//   {2l, 2l+1}. No ds_bpermute/ds_swizzle anywhere in the loop.
// ssrc indices are prefetched two pairs ahead (breaks the idx->row chase);
// rows are prefetched one pair ahead as before.
// One wave per dst node. Agg row (bf16, 256B) written into the FIRST HALF of
// this node's qb_dst row (512B) — row n touched only by wave n, read first.
// ---------------------------------------------------------------------------
__global__ __launch_bounds__(256) void edge_gather(
    const int* __restrict__ rowptr, const int* __restrict__ ssrc,
    unsigned char* __restrict__ qb_dst, const unsigned char* __restrict__ ka_src,
    const unsigned char* __restrict__ vf8,
    const unsigned* __restrict__ We2h, const float* __restrict__ be2f,
    float* __restrict__ spart)
{
    int node = blockIdx.x * 4 + (threadIdx.x >> 6);
    int lane = threadIdx.x & 63;
    int i16  = lane & 15;
    int myh  = lane >> 4;

    // dst-row data: q pair for t, b' 8ch for gate
    const unsigned char* drow = qb_dst + (size_t)node * 512;
    h2 dq = u2h(*(const unsigned*)(drow + lane * 4));
    uint4 dbu = *(const uint4*)(drow + 256 + 16 * i16);
    h2 db0 = u2h(dbu.x), db1 = u2h(dbu.y), db2 = u2h(dbu.z), db3 = u2h(dbu.w);

    // gate weights for this lane's 8 channels, head myh
    uint4 wu = *(const uint4*)(We2h + lane * 4);
    h2 w0 = u2h(wu.x), w1 = u2h(wu.y), w2 = u2h(wu.z), w3 = u2h(wu.w);
    float be2h = be2f[myh];

    int beg = rowptr[node], end = rowptr[node + 1];
    float o0 = 0.f, o1 = 0.f, s_acc = 0.f;

    if (beg < end) {
        int ia = beg, ib = (beg + 1 < end) ? beg + 1 : end - 1;
        int sa = ssrc[ia], sb = ssrc[ib];
        const unsigned char* ra = ka_src + (size_t)sa * 512;
        const unsigned char* rb = ka_src + (size_t)sb * 512;
        unsigned kuA = *(const unsigned*)(ra + lane * 4);
        uint4    auA = *(const uint4*)(ra + 256 + 16 * i16);
        unsigned uvA = *(const unsigned short*)(vf8 + (size_t)sa * OC + 2 * lane);
        unsigned kuB = *(const unsigned*)(rb + lane * 4);
        uint4    auB = *(const uint4*)(rb + 256 + 16 * i16);
        unsigned uvB = *(const unsigned short*)(vf8 + (size_t)sb * OC + 2 * lane);
        int na = (beg + 2 < end) ? beg + 2 : end - 1;
        int nb = (beg + 3 < end) ? beg + 3 : end - 1;
        int sna = ssrc[na], snb = ssrc[nb];

        for (int p = beg; p < end; p += 2) {
            // issue next-pair row loads (indices already resident)
            const unsigned char* rc = ka_src + (size_t)sna * 512;
            const unsigned char* rd = ka_src + (size_t)snb * 512;
            unsigned kuC = *(const unsigned*)(rc + lane * 4);
            uint4    auC = *(const uint4*)(rc + 256 + 16 * i16);
            unsigned uvC = *(const unsigned short*)(vf8 + (size_t)sna * OC + 2 * lane);
            unsigned kuD = *(const unsigned*)(rd + lane * 4);
            uint4    auD = *(const uint4*)(rd + 256 + 16 * i16);
            unsigned uvD = *(const unsigned short*)(vf8 + (size_t)snb * OC + 2 * lane);
            // indices for pair p+4 (consumed next iteration)
            int fa = (p + 4 < end) ? p + 4 : end - 1;
            int fb = (p + 5 < end) ? p + 5 : end - 1;
            int s4a = ssrc[fa], s4b = ssrc[fb];

            bool hasB = (p + 1 < end);

            // t partials (2 ch each)
            float tA = fdot2(u2h(kuA), dq, 0.f);
            float tB = fdot2(u2h(kuB), dq, 0.f);
            // gate partials (8 ch each, head myh)
            h2 hA0 = relu2(u2h(auA.x) + db0);
            h2 hA1 = relu2(u2h(auA.y) + db1);
            h2 hA2 = relu2(u2h(auA.z) + db2);
            h2 hA3 = relu2(u2h(auA.w) + db3);
            h2 hB0 = relu2(u2h(auB.x) + db0);
            h2 hB1 = relu2(u2h(auB.y) + db1);
            h2 hB2 = relu2(u2h(auB.z) + db2);
            h2 hB3 = relu2(u2h(auB.w) + db3);
            float pA = fdot2(hA3, w3, fdot2(hA2, w2, fdot2(hA1, w1, fdot2(hA0, w0, 0.f))));
            float pB = fdot2(hB3, w3, fdot2(hB2, w2, fdot2(hB1, w1, fdot2(hB0, w0, 0.f))));

            // 16-lane DPP allreduce (both scalars, interleaved for ILP)
            tA = DPPADD(tA, 0xB1);  pA = DPPADD(pA, 0xB1);
            tB = DPPADD(tB, 0xB1);  pB = DPPADD(pB, 0xB1);
            tA = DPPADD(tA, 0x4E);  pA = DPPADD(pA, 0x4E);
            tB = DPPADD(tB, 0x4E);  pB = DPPADD(pB, 0x4E);
            tA = DPPADD(tA, 0x128); pA = DPPADD(pA, 0x128);
            tB = DPPADD(tB, 0x128); pB = DPPADD(pB, 0x128);
            tA = DPPADD(tA, 0x124); pA = DPPADD(pA, 0x124);
            tB = DPPADD(tB, 0x124); pB = DPPADD(pB, 0x124);

            float coefA = exp2f(tA * (pA + be2h) * KC);
            float coefB = hasB ? exp2f(tB * (pB + be2h) * KC) : 0.f;
            s_acc += coefA + coefB;

            float vA0, vA1, vB0, vB1;
            fp8x2_to_f32(uvA, vA0, vA1);
            fp8x2_to_f32(uvB, vB0, vB1);
            o0 = fmaf(coefA, vA0, fmaf(coefB, vB0, o0));
            o1 = fmaf(coefA, vA1, fmaf(coefB, vB1, o1));

            kuA = kuC; auA = auC; uvA = uvC;
            kuB = kuD; auB = auD; uvB = uvD;
            sna = s4a; snb = s4b;
        }
    }
    // write agg row (bf16, 256B) into first half of this node's qb row
    *(unsigned*)(qb_dst + (size_t)node * 512 + lane * 4) = f2bu(o0) | (f2bu(o1) << 16);
    if (i16 == 0) spart[node * 4 + myh] = s_acc;
}

// ---------------------------------------------------------------------------
// s_reduce: PARALLEL reduction of spart (NN*4) -> ssum[4] via atomics.
// ---------------------------------------------------------------------------
constexpr int SR_BLOCKS = 98;
__global__ __launch_bounds__(256) void s_reduce(const float* __restrict__ spart,
                                                float* __restrict__ ssum)
{
    int tid = blockIdx.x * 256 + threadIdx.x;
    int h = threadIdx.x & 3;
    float s = 0.f;
    for (int i = tid; i < NN * 4; i += SR_BLOCKS * 256) s += spart[i];
#pragma unroll
    for (int off = 4; off <= 32; off <<= 1) s += __shfl_xor(s, off);
    __shared__ float sm[4][4];
    int lane = threadIdx.x & 63, w = threadIdx.x >> 6;
    if (lane < 4) sm[w][h] = s;
    __syncthreads();
    if (threadIdx.x < 4) {
        float tot = sm[0][h] + sm[1][h] + sm[2][h] + sm[3][h];
        atomicAdd(&ssum[h], tot);
    }
}

// ---------------------------------------------------------------------------
// out_gemm: MFMA out GEMM + fused softmax-normalization + fused LN.
// Agg rows live at stride 512 B inside qb_dst (first half of each row).
// ---------------------------------------------------------------------------
__global__ __launch_bounds__(256) void out_gemm(
    const unsigned char* __restrict__ aggv, const bf16* __restrict__ WoT,
    const void* __restrict__ bo, const void* __restrict__ gamma,
    const void* __restrict__ beta, const unsigned* __restrict__ gw,
    const float* __restrict__ ssum,
    void* __restrict__ out)
{
    const bool f32 = (gw[0] == F32_ONE);
    int wave = threadIdx.x >> 6;
    int lane = threadIdx.x & 63;
    int quad = lane >> 4;
    int l16  = lane & 15;
    int rb = blockIdx.x * 64 + wave * 16;
    int m = rb + l16;
    int ma = (m < NN) ? m : 0;

    const bf16* arow = (const bf16*)(aggv + (size_t)ma * 512);
    short8 a[4];
#pragma unroll
    for (int h = 0; h < 4; ++h) {
        short8 raw = *(const short8*)(arow + h * 32 + quad * 8);
        float invh = 1.0f / ssum[h];
#pragma unroll
        for (int jj = 0; jj < 8; ++jj) {
            float f = __uint_as_float(((unsigned)(unsigned short)raw[jj]) << 16) * invh;
            raw[jj] = (short)f2bu(f);
        }
        a[h] = raw;
    }

    float o[8][4];
#pragma unroll
    for (int t = 0; t < 8; ++t) {
        const bf16* bp = WoT + (size_t)(t * 16 + l16) * OC + quad * 8;
        f32x4 acc = {0.f, 0.f, 0.f, 0.f};
#pragma unroll
        for (int h = 0; h < 4; ++h) {
            short8 bfr = *(const short8*)(bp + h * 32);
            acc = __builtin_amdgcn_mfma_f32_16x16x32_bf16(a[h], bfr, acc, 0, 0, 0);
        }
        float bias = ldf(bo, t * 16 + l16, f32);
#pragma unroll
        for (int r = 0; r < 4; ++r) o[t][r] = acc[r] + bias;
    }

#pragma unroll
    for (int r = 0; r < 4; ++r) {
        float s1 = 0.f, s2 = 0.f;
#pragma unroll
        for (int t = 0; t < 8; ++t) { s1 += o[t][r]; s2 += o[t][r] * o[t][r]; }
#pragma unroll
        for (int off = 1; off <= 8; off <<= 1) {
            s1 += __shfl_xor(s1, off);
            s2 += __shfl_xor(s2, off);
        }
        float mu = s1 * (1.0f / OC);
        float var = fmaxf(s2 * (1.0f / OC) - mu * mu, 0.f);
        float rs = rsqrtf(var + 1e-5f);
        int node = rb + quad * 4 + r;
        if (node < NN) {
#pragma unroll
            for (int t = 0; t < 8; ++t) {
                int col = t * 16 + l16;
                float y = (o[t][r] - mu) * rs * ldf(gamma, col, f32) + ldf(beta, col, f32);
                if (f32) ((float*)out)[(size_t)node * OC + col] = y;
                else     ((bf16*)out)[(size_t)node * OC + col] = __float2bfloat16(y);
            }
        }
    }
}

// ---------------------------------------------------------------------------
extern "C" void kernel_launch(void* const* d_in, const int* in_sizes, int n_in,
                              void* d_out, int out_size, void* d_ws, size_t ws_size,
                              hipStream_t stream)
{
    int p = 0;
    const void* x   = d_in[p++];
    const void* eia = d_in[p++];
    const void* eib = eia;
    int split = 0;
    if (n_in >= 17) { eib = d_in[p++]; split = 1; }
    const void* Wq   = d_in[p++];
    const void* bq   = d_in[p++];
    const void* Wk   = d_in[p++];
    const void* bk   = d_in[p++];
    const void* Wv   = d_in[p++];
    const void* bv   = d_in[p++];
    const void* We1  = d_in[p++];
    const void* be1  = d_in[p++];
    const void* We2  = d_in[p++];
    const void* be2  = d_in[p++];
    const void* Wo   = d_in[p++];
    const void* bo   = d_in[p++];
    const void* gamma= d_in[p++];
    const void* beta = d_in[p++];
    const unsigned* gw = (const unsigned*)gamma;

    // workspace layout (~69 MB). cnt and ssum adjacent -> single memset.
    char* w = (char*)d_ws;
    bf16*  xb     = (bf16*)w;                  w += (size_t)NN * IC * 2;  // 6.4 MB
    unsigned char* qb_dst = (unsigned char*)w; w += (size_t)NN * 512;     // 25.6 MB (f16 q|b')
    unsigned char* ka_src = (unsigned char*)w; w += (size_t)NN * 512;     // 25.6 MB (f16 k|a)
    unsigned char* vf8    = (unsigned char*)w; w += (size_t)NN * OC;      // 6.4 MB
    int*   ssrc   = (int*)w;                   w += (size_t)NE * 4;       // 3.2 MB
    int*   cnt    = (int*)w;                   w += (size_t)NN * 4;       // 200 KB
    float* ssum   = (float*)w;                 w += 8 * 4;                // (memset w/ cnt)
    int*   rowptr = (int*)w;                   w += (size_t)(NN + 4) * 4; // padded to 16B
    int*   cursor = (int*)w;                   w += (size_t)NN * 4;
    float* spart  = (float*)w;                 w += (size_t)NN * 4 * 4;   // 800 KB
    unsigned* We2h = (unsigned*)w;             w += 256 * 4;              // 1 KB
    float* be2f   = (float*)w;                 w += NH * 4;
    bf16*  WcatT  = (bf16*)w;                  w += (size_t)5 * OC * IC * 2;
    float* bcat   = (float*)w;                 w += 5 * OC * 4;
    bf16*  WoT    = (bf16*)w;                  w += (size_t)OC * OC * 2;

    if (ws_size < (size_t)((char*)w - (char*)d_ws)) return;

    hipMemsetAsync(cnt, 0, (size_t)NN * 4 + 32, stream);   // cnt + ssum
    prep<<<PB_X + PB_W + PB_WO + PB_CNT + 1, 256, 0, stream>>>(
        x, Wq, bq, Wk, bk, Wv, bv, We1, be1, We2, be2, Wo, gw,
        eia, eib, split,
        xb, WcatT, WoT, cnt, We2h, be2f, bcat);
    csr_scan<<<1, 1024, 0, stream>>>(cnt, rowptr, cursor);
    node_gemm<<<NG_GEMM + NG_FILL, 256, 0, stream>>>(
        xb, WcatT, bcat, qb_dst, ka_src, vf8, eia, eib, split, cursor, ssrc);
    edge_gather<<<NN / 4, 256, 0, stream>>>(rowptr, ssrc, qb_dst, ka_src, vf8,
                                            We2h, be2f, spart);
    s_reduce<<<SR_BLOCKS, 256, 0, stream>>>(spart, ssum);
    out_gemm<<<(NN + 63) / 64, 256, 0, stream>>>(qb_dst, WoT, bo, gamma, beta, gw,
                                                 ssum, d_out);
}

// Round 2
// 335.234 us; speedup vs baseline: 1.5367x; 1.3674x over previous
//
#include <hip/hip_runtime.h>
#include <hip/hip_bf16.h>

typedef __hip_bfloat16 bf16;
typedef __attribute__((ext_vector_type(8))) short short8;   // 8 bf16 (4 VGPRs)
typedef __attribute__((ext_vector_type(4))) float f32x4;    // 4 fp32 acc
typedef __attribute__((ext_vector_type(2))) float f32x2;
typedef _Float16 h2 __attribute__((ext_vector_type(2)));    // packed half2

constexpr int NN = 50000;   // nodes
constexpr int NE = 800000;  // edges
constexpr int IC = 64;      // in channels
constexpr int OC = 128;     // out channels
constexpr int NH = 4;       // heads
constexpr unsigned F32_ONE = 0x3F800000u;
// 1/sqrt(32) * log2(e): exp(l) = exp2(l*log2e), constants fused
constexpr float KC = 0.25503486f;

__device__ __forceinline__ float ldf(const void* p, int i, bool f32) {
    return f32 ? ((const float*)p)[i]
               : __bfloat162float(((const bf16*)p)[i]);
}

__device__ __forceinline__ int ld_idx(const void* p, long long i, bool i64) {
    return i64 ? (int)((const long long*)p)[i] : ((const int*)p)[i];
}

__device__ __forceinline__ bool probe_i64(const void* ei) {
    const unsigned* u = (const unsigned*)ei;
    return (u[1] | u[3] | u[5] | u[7]) == 0u;
}

// f32 -> bf16 bits (RNE)
__device__ __forceinline__ unsigned f2bu(float x) {
    unsigned u = __float_as_uint(x);
    return (u + 0x7FFFu + ((u >> 16) & 1u)) >> 16;
}

__device__ __forceinline__ h2 u2h(unsigned u) { return __builtin_bit_cast(h2, u); }

// dot2: c += a[0]*b[0] + a[1]*b[1] (f16 inputs, f32 accum)
__device__ __forceinline__ float fdot2(h2 a, h2 b, float c) {
#if __has_builtin(__builtin_amdgcn_fdot2)
    return __builtin_amdgcn_fdot2(a, b, c, false);
#else
    return c + (float)a[0] * (float)b[0] + (float)a[1] * (float)b[1];
#endif
}

__device__ __forceinline__ h2 relu2(h2 a) {
    h2 z = {(_Float16)0.f, (_Float16)0.f};
#if __has_builtin(__builtin_elementwise_max)
    return __builtin_elementwise_max(a, z);
#else
    h2 r;
    r[0] = a[0] > (_Float16)0.f ? a[0] : (_Float16)0.f;
    r[1] = a[1] > (_Float16)0.f ? a[1] : (_Float16)0.f;
    return r;
#endif
}

// DPP-based add of a lane-permuted copy (VALU pipe; NO ds_bpermute).
// ctrl: 0xB1 = quad_perm xor1, 0x4E = quad_perm xor2,
//       0x128 = row_ror:8 (== xor8 within 16-row), 0x124 = row_ror:4.
// Sequence xor1,xor2,ror8,ror4 = full 16-lane allreduce (all lanes get sum).
#define DPPADD(x, ctrl) \
    ((x) + __int_as_float(__builtin_amdgcn_mov_dpp(__float_as_int(x), (ctrl), 0xF, 0xF, false)))

// ---- fp8 e4m3 helpers ------------------------------------------------------
__device__ __forceinline__ unsigned char f32_to_fp8(float x) {
#if __has_builtin(__builtin_amdgcn_cvt_pk_fp8_f32)
    return (unsigned char)(__builtin_amdgcn_cvt_pk_fp8_f32(x, x, 0, false) & 0xFF);
#else
    unsigned bits = __float_as_uint(x);
    unsigned s = bits >> 31;
    float a = fabsf(x);
    if (a >= 448.f) return (unsigned char)((s << 7) | 0x7E);
    if (a < 0.015625f) {
        int m = (int)(a * 512.f + 0.5f);
        if (m >= 8) return (unsigned char)((s << 7) | 0x08);
        return (unsigned char)((s << 7) | m);
    }
    unsigned ab = (bits & 0x7FFFFFFFu) + 0x00080000u;
    int e8 = (int)(ab >> 23) - 127 + 7;
    unsigned m3 = (ab >> 20) & 7u;
    if (e8 >= 16) return (unsigned char)((s << 7) | 0x7E);
    return (unsigned char)((s << 7) | ((unsigned)e8 << 3) | m3);
#endif
}

__device__ __forceinline__ void fp8x2_to_f32(unsigned u, float& f0, float& f1) {
#if __has_builtin(__builtin_amdgcn_cvt_pk_f32_fp8)
    f32x2 lo = __builtin_amdgcn_cvt_pk_f32_fp8(u, false);
    f0 = lo[0]; f1 = lo[1];
#else
    float r[2];
#pragma unroll
    for (int j = 0; j < 2; ++j) {
        unsigned b = (u >> (8 * j)) & 0xFF;
        unsigned s = b >> 7, e = (b >> 3) & 15, m = b & 7;
        float v = (e == 0) ? (float)m * 0.001953125f
                           : __uint_as_float(((e + 120u) << 23) | (m << 20));
        r[j] = s ? -v : v;
    }
    f0 = r[0]; f1 = r[1];
#endif
}

// ---------------------------------------------------------------------------
// prep: fused one-shot conversions + csr_count. (cnt/ssum zeroed by memset)
// bcat: [0,128)=bq, [128,256)=bk, [256,384)=bv, [384,512)=0 (a), [512,640)=be1 (b')
// We2h packing (for edge_gather's 16-lane scheme): entry t = lane*4 + k,
//   lane: g = lane>>4 (head), i = lane&15; pair index pp = 4*i + k;
//   value = half2( We2[2pp][g], We2[2pp+1][g] ).
// ---------------------------------------------------------------------------
constexpr int PB_X   = 12500;
constexpr int PB_W   = 160;
constexpr int PB_WO  = 64;
constexpr int PB_CNT = 3125;   // csr_count: NE/256

__global__ __launch_bounds__(256) void prep(
    const void* __restrict__ x,
    const void* __restrict__ Wq, const void* __restrict__ bq,
    const void* __restrict__ Wk, const void* __restrict__ bk,
    const void* __restrict__ Wv, const void* __restrict__ bv,
    const void* __restrict__ We1, const void* __restrict__ be1,
    const void* __restrict__ We2, const void* __restrict__ be2,
    const void* __restrict__ Wo,  const unsigned* __restrict__ gw,
    const void* __restrict__ eia, const void* __restrict__ eib, int split,
    bf16* __restrict__ xb, bf16* __restrict__ WcatT, bf16* __restrict__ WoT,
    int* __restrict__ cnt,
    unsigned* __restrict__ We2h, float* __restrict__ be2f,
    float* __restrict__ bcat)
{
    const bool f32 = (gw[0] == F32_ONE);
    int b = blockIdx.x, t = threadIdx.x;
    if (b < PB_X) {
        int i = b * 256 + t;
        if (i < NN * IC) xb[i] = __float2bfloat16(ldf(x, i, f32));
    } else if (b < PB_X + PB_W) {
        int idx = (b - PB_X) * 256 + t;         // n*64 + k
        int n = idx >> 6, k = idx & 63;
        int sel = n >> 7, c = n & 127;
        float v;
        if (sel == 0)      v = ldf(Wq, k * OC + c, f32);
        else if (sel == 1) v = ldf(Wk, k * OC + c, f32);
        else if (sel == 2) v = ldf(Wv, k * OC + c, f32);
        else if (sel == 3) v = ldf(We1, k * OC + c, f32);
        else               v = ldf(We1, (IC + k) * OC + c, f32);
        WcatT[idx] = __float2bfloat16(v);
    } else if (b < PB_X + PB_W + PB_WO) {
        int idx = (b - PB_X - PB_W) * 256 + t;  // n*128 + k
        int n = idx >> 7, k = idx & 127;
        WoT[idx] = __float2bfloat16(ldf(Wo, k * OC + n, f32));
    } else if (b < PB_X + PB_W + PB_WO + PB_CNT) {
        const bool i64 = probe_i64(eia);
        long long e = (long long)(b - PB_X - PB_W - PB_WO) * 256 + t;
        int d = split ? ld_idx(eib, e, i64) : ld_idx(eia, NE + e, i64);
        atomicAdd(&cnt[d], 1);
    } else {
        if (t < NH) be2f[t] = ldf(be2, t, f32);
        // We2h: 64 lanes x 4 dwords, per-lane 8-channel weight slice for ONE head
        {
            int ln = t >> 2, k = t & 3;         // t in [0,256)
            int g = ln >> 4, ii = ln & 15;
            int pp = 4 * ii + k;
            h2 hv;
            hv[0] = (_Float16)ldf(We2, (2 * pp) * NH + g, f32);
            hv[1] = (_Float16)ldf(We2, (2 * pp + 1) * NH + g, f32);
            We2h[t] = __builtin_bit_cast(unsigned, hv);
        }
        for (int n = t; n < 5 * OC; n += 256) {
            int sel = n >> 7, c = n & 127;
            float bb = 0.f;
            if (sel == 0) bb = ldf(bq, c, f32);
            else if (sel == 1) bb = ldf(bk, c, f32);
            else if (sel == 2) bb = ldf(bv, c, f32);
            else if (sel == 4) bb = ldf(be1, c, f32);  // fold be1 into b'
            bcat[n] = bb;
        }
    }
}

// ---------------------------------------------------------------------------
// Parallel CSR scan (replaces the single-block csr_scan that was 125 us):
//   scan_part: 49 blocks x 1024 elems — block sums -> bsum[b]; rowptr[NN]=NE.
//   scan_fin : 49 blocks — wave0 reduces bsum[0..b) (49 ints, cheaper than a
//              3rd kernel), 64-lane shfl_up inclusive scan + cross-wave LDS
//              fixup, int4 stores of rowptr/cursor.
// ---------------------------------------------------------------------------
constexpr int SCAN_NB = 49;   // 49*1024 = 50176 >= NN; NN%4==0 so int4 ok

__global__ __launch_bounds__(256) void scan_part(const int* __restrict__ cnt,
                                                 int* __restrict__ bsum,
                                                 int* __restrict__ rowptr)
{
    int b = blockIdx.x, t = threadIdx.x;
    int base = b * 1024 + t * 4;
    int4 v;
    if (base < NN) v = *(const int4*)(cnt + base);
    else { v.x = 0; v.y = 0; v.z = 0; v.w = 0; }
    int s = v.x + v.y + v.z + v.w;
#pragma unroll
    for (int off = 1; off < 64; off <<= 1) s += __shfl_xor(s, off);
    __shared__ int sm[4];
    int lane = t & 63, w = t >> 6;
    if (lane == 0) sm[w] = s;
    __syncthreads();
    if (t == 0) bsum[b] = sm[0] + sm[1] + sm[2] + sm[3];
    if (b == 0 && t == 0) rowptr[NN] = NE;   // counts always sum to NE
}

__global__ __launch_bounds__(256) void scan_fin(const int* __restrict__ cnt,
                                                const int* __restrict__ bsum,
                                                int* __restrict__ rowptr,
                                                int* __restrict__ cursor)
{
    int b = blockIdx.x, t = threadIdx.x;
    int lane = t & 63, w = t >> 6;
    __shared__ int s_boff;
    __shared__ int wsum[4];
    if (w == 0) {
        int pre = (lane < b) ? bsum[lane] : 0;   // b <= 48 < 64
#pragma unroll
        for (int off = 1; off < 64; off <<= 1) pre += __shfl_xor(pre, off);
        if (lane == 0) s_boff = pre;
    }
    int base = b * 1024 + t * 4;
    int4 v;
    if (base < NN) v = *(const int4*)(cnt + base);
    else { v.x = 0; v.y = 0; v.z = 0; v.w = 0; }
    int s = v.x + v.y + v.z + v.w;
    int inc = s;
#pragma unroll
    for (int off = 1; off < 64; off <<= 1) {
        int u = __shfl_up(inc, off);
        if (lane >= off) inc += u;
    }
    if (lane == 63) wsum[w] = inc;
    __syncthreads();
    int run = s_boff + (inc - s);
#pragma unroll
    for (int i = 0; i < 3; ++i) if (i < w) run += wsum[i];
    if (base < NN) {
        int4 rp;
        rp.x = run;
        rp.y = rp.x + v.x;
        rp.z = rp.y + v.y;
        rp.w = rp.z + v.z;
        *(int4*)(rowptr + base) = rp;
        *(int4*)(cursor + base) = rp;
    }
}

// ---------------------------------------------------------------------------
// node_gemm (+fused csr_fill): blocks [0,3125) GEMM, [3125,6250) fill.
// GEMM: D[50000 x 640] = xb @ Wcat + bcat (MFMA).
// Outputs: qb_dst row (f16, 512B) = [q 128ch | b' 128ch];
//          ka_src row (f16, 512B) = [k 128ch | a 128ch]; vf8 row 128B (fp8).
// ---------------------------------------------------------------------------
constexpr int NG_GEMM = 3125;   // NN/16
constexpr int NG_FILL = 3125;   // NE/256

__global__ __launch_bounds__(256) void node_gemm(
    const bf16* __restrict__ xb, const bf16* __restrict__ WcatT,
    const float* __restrict__ bcat,
    unsigned char* __restrict__ qb_dst, unsigned char* __restrict__ ka_src,
    unsigned char* __restrict__ vf8,
    const void* __restrict__ eia, const void* __restrict__ eib, int split,
    int* __restrict__ cursor, int* __restrict__ ssrc)
{
    if (blockIdx.x >= NG_GEMM) {
        // ---- csr_fill ----
        const bool i64 = probe_i64(eia);
        long long e = (long long)(blockIdx.x - NG_GEMM) * 256 + threadIdx.x;
        int s = ld_idx(eia, e, i64);
        int d = split ? ld_idx(eib, e, i64) : ld_idx(eia, NE + e, i64);
        int pos = atomicAdd(&cursor[d], 1);
        ssrc[pos] = s;
        return;
    }
    int wave = threadIdx.x >> 6;
    int lane = threadIdx.x & 63;
    int quad = lane >> 4;
    int l16  = lane & 15;
    int row_base = blockIdx.x * 16;
    int m = row_base + l16;

    short8 a0 = *(const short8*)(xb + (size_t)m * IC + quad * 8);
    short8 a1 = *(const short8*)(xb + (size_t)m * IC + 32 + quad * 8);

    _Float16* qh = (_Float16*)qb_dst;
    _Float16* kh = (_Float16*)ka_src;

#pragma unroll
    for (int t = 0; t < 10; ++t) {
        int colbase = wave * 160 + t * 16;
        const bf16* bp = WcatT + (size_t)(colbase + l16) * IC + quad * 8;
        short8 b0 = *(const short8*)(bp);
        short8 b1 = *(const short8*)(bp + 32);
        f32x4 acc = {0.f, 0.f, 0.f, 0.f};
        acc = __builtin_amdgcn_mfma_f32_16x16x32_bf16(a0, b0, acc, 0, 0, 0);
        acc = __builtin_amdgcn_mfma_f32_16x16x32_bf16(a1, b1, acc, 0, 0, 0);

        float bias = bcat[colbase + l16];
        int sel = colbase >> 7;
        int cc  = (colbase & 127) + l16;
#pragma unroll
        for (int r = 0; r < 4; ++r) {
            int node = row_base + quad * 4 + r;
            float fv = acc[r] + bias;
            if (sel == 2) {
                vf8[(size_t)node * OC + cc] = f32_to_fp8(fv);
            } else {
                _Float16 val = (_Float16)fv;
                if (sel == 0)      qh[(size_t)node * 256 + cc] = val;
                else if (sel == 1) kh[(size_t)node * 256 + cc] = val;
                else if (sel == 3) kh[(size_t)node * 256 + 128 + cc] = val;
                else               qh[(size_t)node * 256 + 128 + cc] = val;
            }
        }
    }
}

// ---------------------------------------------------------------------------
// edge_gather: FUSED edge logit + softmax-weighted aggregation, 2-edge ILP.
// 16-lane-partition scheme (zero LDS-pipe ops):
//   lane l: head g = l>>4, i = l&15.
//   t-partial: q/k channels {2l, 2l+1}  (dword at byte 4l of the 256B half)
//   p-partial: gate channels [8i, 8i+8) for head g (uint4 of a/b' + uint4 We2h)
//   Both reduced with a 4-step DPP allreduce confined to each 16-lane row
//   (quad_perm xor1, xor2, row_ror:8, row_ror:4) -> every lane holds t_g, p_g
//   for its own head g == l>>4, which is exactly the head of its v channels
//   {2l, 2l+1}. No ds_bpermute/ds_swizzle anywhere in the loop.
// ssrc indices are prefetched two pairs ahead (breaks the idx->row chase);
// rows are prefetched one pair ahead as before.
// One wave per dst node. Agg row (bf16, 256B) written into the FIRST HALF of
// this node's qb_dst row (512B) — row n touched only by wave n, read first.
// ---------------------------------------------------------------------------
__global__ __launch_bounds__(256) void edge_gather(
    const int* __restrict__ rowptr, const int* __restrict__ ssrc,
    unsigned char* __restrict__ qb_dst, const unsigned char* __restrict__ ka_src,
    const unsigned char* __restrict__ vf8,
    const unsigned* __restrict__ We2h, const float* __restrict__ be2f,
    float* __restrict__ spart)
{
    int node = blockIdx.x * 4 + (threadIdx.x >> 6);
    int lane = threadIdx.x & 63;
    int i16  = lane & 15;
    int myh  = lane >> 4;

    // dst-row data: q pair for t, b' 8ch for gate
    const unsigned char* drow = qb_dst + (size_t)node * 512;
    h2 dq = u2h(*(const unsigned*)(drow + lane * 4));
    uint4 dbu = *(const uint4*)(drow + 256 + 16 * i16);
    h2 db0 = u2h(dbu.x), db1 = u2h(dbu.y), db2 = u2h(dbu.z), db3 = u2h(dbu.w);

    // gate weights for this lane's 8 channels, head myh
    uint4 wu = *(const uint4*)(We2h + lane * 4);
    h2 w0 = u2h(wu.x), w1 = u2h(wu.y), w2 = u2h(wu.z), w3 = u2h(wu.w);
    float be2h = be2f[myh];

    int beg = rowptr[node], end = rowptr[node + 1];
    float o0 = 0.f, o1 = 0.f, s_acc = 0.f;

    if (beg < end) {
        int ia = beg, ib = (beg + 1 < end) ? beg + 1 : end - 1;
        int sa = ssrc[ia], sb = ssrc[ib];
        const unsigned char* ra = ka_src + (size_t)sa * 512;
        const unsigned char* rb = ka_src + (size_t)sb * 512;
        unsigned kuA = *(const unsigned*)(ra + lane * 4);
        uint4    auA = *(const uint4*)(ra + 256 + 16 * i16);
        unsigned uvA = *(const unsigned short*)(vf8 + (size_t)sa * OC + 2 * lane);
        unsigned kuB = *(const unsigned*)(rb + lane * 4);
        uint4    auB = *(const uint4*)(rb + 256 + 16 * i16);
        unsigned uvB = *(const unsigned short*)(vf8 + (size_t)sb * OC + 2 * lane);
        int na = (beg + 2 < end) ? beg + 2 : end - 1;
        int nb = (beg + 3 < end) ? beg + 3 : end - 1;
        int sna = ssrc[na], snb = ssrc[nb];

        for (int p = beg; p < end; p += 2) {
            // issue next-pair row loads (indices already resident)
            const unsigned char* rc = ka_src + (size_t)sna * 512;
            const unsigned char* rd = ka_src + (size_t)snb * 512;
            unsigned kuC = *(const unsigned*)(rc + lane * 4);
            uint4    auC = *(const uint4*)(rc + 256 + 16 * i16);
            unsigned uvC = *(const unsigned short*)(vf8 + (size_t)sna * OC + 2 * lane);
            unsigned kuD = *(const unsigned*)(rd + lane * 4);
            uint4    auD = *(const uint4*)(rd + 256 + 16 * i16);
            unsigned uvD = *(const unsigned short*)(vf8 + (size_t)snb * OC + 2 * lane);
            // indices for pair p+4 (consumed next iteration)
            int fa = (p + 4 < end) ? p + 4 : end - 1;
            int fb = (p + 5 < end) ? p + 5 : end - 1;
            int s4a = ssrc[fa], s4b = ssrc[fb];

            bool hasB = (p + 1 < end);

            // t partials (2 ch each)
            float tA = fdot2(u2h(kuA), dq, 0.f);
            float tB = fdot2(u2h(kuB), dq, 0.f);
            // gate partials (8 ch each, head myh)
            h2 hA0 = relu2(u2h(auA.x) + db0);
            h2 hA1 = relu2(u2h(auA.y) + db1);
            h2 hA2 = relu2(u2h(auA.z) + db2);
            h2 hA3 = relu2(u2h(auA.w) + db3);
            h2 hB0 = relu2(u2h(auB.x) + db0);
            h2 hB1 = relu2(u2h(auB.y) + db1);
            h2 hB2 = relu2(u2h(auB.z) + db2);
            h2 hB3 = relu2(u2h(auB.w) + db3);
            float pA = fdot2(hA3, w3, fdot2(hA2, w2, fdot2(hA1, w1, fdot2(hA0, w0, 0.f))));
            float pB = fdot2(hB3, w3, fdot2(hB2, w2, fdot2(hB1, w1, fdot2(hB0, w0, 0.f))));

            // 16-lane DPP allreduce (both scalars, interleaved for ILP)
            tA = DPPADD(tA, 0xB1);  pA = DPPADD(pA, 0xB1);
            tB = DPPADD(tB, 0xB1);  pB = DPPADD(pB, 0xB1);
            tA = DPPADD(tA, 0x4E);  pA = DPPADD(pA, 0x4E);
            tB = DPPADD(tB, 0x4E);  pB = DPPADD(pB, 0x4E);
            tA = DPPADD(tA, 0x128); pA = DPPADD(pA, 0x128);
            tB = DPPADD(tB, 0x128); pB = DPPADD(pB, 0x128);
            tA = DPPADD(tA, 0x124); pA = DPPADD(pA, 0x124);
            tB = DPPADD(tB, 0x124); pB = DPPADD(pB, 0x124);

            float coefA = exp2f(tA * (pA + be2h) * KC);
            float coefB = hasB ? exp2f(tB * (pB + be2h) * KC) : 0.f;
            s_acc += coefA + coefB;

            float vA0, vA1, vB0, vB1;
            fp8x2_to_f32(uvA, vA0, vA1);
            fp8x2_to_f32(uvB, vB0, vB1);
            o0 = fmaf(coefA, vA0, fmaf(coefB, vB0, o0));
            o1 = fmaf(coefA, vA1, fmaf(coefB, vB1, o1));

            kuA = kuC; auA = auC; uvA = uvC;
            kuB = kuD; auB = auD; uvB = uvD;
            sna = s4a; snb = s4b;
        }
    }
    // write agg row (bf16, 256B) into first half of this node's qb row
    *(unsigned*)(qb_dst + (size_t)node * 512 + lane * 4) = f2bu(o0) | (f2bu(o1) << 16);
    if (i16 == 0) spart[node * 4 + myh] = s_acc;
}

// ---------------------------------------------------------------------------
// s_reduce: PARALLEL reduction of spart (NN*4) -> ssum[4] via atomics.
// ---------------------------------------------------------------------------
constexpr int SR_BLOCKS = 98;
__global__ __launch_bounds__(256) void s_reduce(const float* __restrict__ spart,
                                                float* __restrict__ ssum)
{
    int tid = blockIdx.x * 256 + threadIdx.x;
    int h = threadIdx.x & 3;
    float s = 0.f;
    for (int i = tid; i < NN * 4; i += SR_BLOCKS * 256) s += spart[i];
#pragma unroll
    for (int off = 4; off <= 32; off <<= 1) s += __shfl_xor(s, off);
    __shared__ float sm[4][4];
    int lane = threadIdx.x & 63, w = threadIdx.x >> 6;
    if (lane < 4) sm[w][h] = s;
    __syncthreads();
    if (threadIdx.x < 4) {
        float tot = sm[0][h] + sm[1][h] + sm[2][h] + sm[3][h];
        atomicAdd(&ssum[h], tot);
    }
}

// ---------------------------------------------------------------------------
// out_gemm: MFMA out GEMM + fused softmax-normalization + fused LN.
// Agg rows live at stride 512 B inside qb_dst (first half of each row).
// ---------------------------------------------------------------------------
__global__ __launch_bounds__(256) void out_gemm(
    const unsigned char* __restrict__ aggv, const bf16* __restrict__ WoT,
    const void* __restrict__ bo, const void* __restrict__ gamma,
    const void* __restrict__ beta, const unsigned* __restrict__ gw,
    const float* __restrict__ ssum,
    void* __restrict__ out)
{
    const bool f32 = (gw[0] == F32_ONE);
    int wave = threadIdx.x >> 6;
    int lane = threadIdx.x & 63;
    int quad = lane >> 4;
    int l16  = lane & 15;
    int rb = blockIdx.x * 64 + wave * 16;
    int m = rb + l16;
    int ma = (m < NN) ? m : 0;

    const bf16* arow = (const bf16*)(aggv + (size_t)ma * 512);
    short8 a[4];
#pragma unroll
    for (int h = 0; h < 4; ++h) {
        short8 raw = *(const short8*)(arow + h * 32 + quad * 8);
        float invh = 1.0f / ssum[h];
#pragma unroll
        for (int jj = 0; jj < 8; ++jj) {
            float f = __uint_as_float(((unsigned)(unsigned short)raw[jj]) << 16) * invh;
            raw[jj] = (short)f2bu(f);
        }
        a[h] = raw;
    }

    float o[8][4];
#pragma unroll
    for (int t = 0; t < 8; ++t) {
        const bf16* bp = WoT + (size_t)(t * 16 + l16) * OC + quad * 8;
        f32x4 acc = {0.f, 0.f, 0.f, 0.f};
#pragma unroll
        for (int h = 0; h < 4; ++h) {
            short8 bfr = *(const short8*)(bp + h * 32);
            acc = __builtin_amdgcn_mfma_f32_16x16x32_bf16(a[h], bfr, acc, 0, 0, 0);
        }
        float bias = ldf(bo, t * 16 + l16, f32);
#pragma unroll
        for (int r = 0; r < 4; ++r) o[t][r] = acc[r] + bias;
    }

#pragma unroll
    for (int r = 0; r < 4; ++r) {
        float s1 = 0.f, s2 = 0.f;
#pragma unroll
        for (int t = 0; t < 8; ++t) { s1 += o[t][r]; s2 += o[t][r] * o[t][r]; }
#pragma unroll
        for (int off = 1; off <= 8; off <<= 1) {
            s1 += __shfl_xor(s1, off);
            s2 += __shfl_xor(s2, off);
        }
        float mu = s1 * (1.0f / OC);
        float var = fmaxf(s2 * (1.0f / OC) - mu * mu, 0.f);
        float rs = rsqrtf(var + 1e-5f);
        int node = rb + quad * 4 + r;
        if (node < NN) {
#pragma unroll
            for (int t = 0; t < 8; ++t) {
                int col = t * 16 + l16;
                float y = (o[t][r] - mu) * rs * ldf(gamma, col, f32) + ldf(beta, col, f32);
                if (f32) ((float*)out)[(size_t)node * OC + col] = y;
                else     ((bf16*)out)[(size_t)node * OC + col] = __float2bfloat16(y);
            }
        }
    }
}

// ---------------------------------------------------------------------------
extern "C" void kernel_launch(void* const* d_in, const int* in_sizes, int n_in,
                              void* d_out, int out_size, void* d_ws, size_t ws_size,
                              hipStream_t stream)
{
    int p = 0;
    const void* x   = d_in[p++];
    const void* eia = d_in[p++];
    const void* eib = eia;
    int split = 0;
    if (n_in >= 17) { eib = d_in[p++]; split = 1; }
    const void* Wq   = d_in[p++];
    const void* bq   = d_in[p++];
    const void* Wk   = d_in[p++];
    const void* bk   = d_in[p++];
    const void* Wv   = d_in[p++];
    const void* bv   = d_in[p++];
    const void* We1  = d_in[p++];
    const void* be1  = d_in[p++];
    const void* We2  = d_in[p++];
    const void* be2  = d_in[p++];
    const void* Wo   = d_in[p++];
    const void* bo   = d_in[p++];
    const void* gamma= d_in[p++];
    const void* beta = d_in[p++];
    const unsigned* gw = (const unsigned*)gamma;

    // workspace layout (~69 MB). cnt and ssum adjacent -> single memset.
    char* w = (char*)d_ws;
    bf16*  xb     = (bf16*)w;                  w += (size_t)NN * IC * 2;  // 6.4 MB
    unsigned char* qb_dst = (unsigned char*)w; w += (size_t)NN * 512;     // 25.6 MB (f16 q|b')
    unsigned char* ka_src = (unsigned char*)w; w += (size_t)NN * 512;     // 25.6 MB (f16 k|a)
    unsigned char* vf8    = (unsigned char*)w; w += (size_t)NN * OC;      // 6.4 MB
    int*   ssrc   = (int*)w;                   w += (size_t)NE * 4;       // 3.2 MB
    int*   cnt    = (int*)w;                   w += (size_t)NN * 4;       // 200 KB
    float* ssum   = (float*)w;                 w += 8 * 4;                // (memset w/ cnt)
    int*   rowptr = (int*)w;                   w += (size_t)(NN + 4) * 4; // padded to 16B
    int*   cursor = (int*)w;                   w += (size_t)NN * 4;
    int*   bsum   = (int*)w;                   w += 64 * 4;               // scan block sums
    float* spart  = (float*)w;                 w += (size_t)NN * 4 * 4;   // 800 KB
    unsigned* We2h = (unsigned*)w;             w += 256 * 4;              // 1 KB
    float* be2f   = (float*)w;                 w += NH * 4;
    bf16*  WcatT  = (bf16*)w;                  w += (size_t)5 * OC * IC * 2;
    float* bcat   = (float*)w;                 w += 5 * OC * 4;
    bf16*  WoT    = (bf16*)w;                  w += (size_t)OC * OC * 2;

    if (ws_size < (size_t)((char*)w - (char*)d_ws)) return;

    hipMemsetAsync(cnt, 0, (size_t)NN * 4 + 32, stream);   // cnt + ssum
    prep<<<PB_X + PB_W + PB_WO + PB_CNT + 1, 256, 0, stream>>>(
        x, Wq, bq, Wk, bk, Wv, bv, We1, be1, We2, be2, Wo, gw,
        eia, eib, split,
        xb, WcatT, WoT, cnt, We2h, be2f, bcat);
    scan_part<<<SCAN_NB, 256, 0, stream>>>(cnt, bsum, rowptr);
    scan_fin<<<SCAN_NB, 256, 0, stream>>>(cnt, bsum, rowptr, cursor);
    node_gemm<<<NG_GEMM + NG_FILL, 256, 0, stream>>>(
        xb, WcatT, bcat, qb_dst, ka_src, vf8, eia, eib, split, cursor, ssrc);
    edge_gather<<<NN / 4, 256, 0, stream>>>(rowptr, ssrc, qb_dst, ka_src, vf8,
                                            We2h, be2f, spart);
    s_reduce<<<SR_BLOCKS, 256, 0, stream>>>(spart, ssum);
    out_gemm<<<(NN + 63) / 64, 256, 0, stream>>>(qb_dst, WoT, bo, gamma, beta, gw,
                                                 ssum, d_out);
}

// Round 3
// 322.537 us; speedup vs baseline: 1.5971x; 1.0394x over previous
//
#include <hip/hip_runtime.h>
#include <hip/hip_bf16.h>

typedef __hip_bfloat16 bf16;
typedef __attribute__((ext_vector_type(8))) short short8;   // 8 bf16 (4 VGPRs)
typedef __attribute__((ext_vector_type(4))) float f32x4;    // 4 fp32 acc
typedef __attribute__((ext_vector_type(2))) float f32x2;
typedef _Float16 h2 __attribute__((ext_vector_type(2)));    // packed half2

constexpr int NN = 50000;   // nodes
constexpr int NE = 800000;  // edges
constexpr int IC = 64;      // in channels
constexpr int OC = 128;     // out channels
constexpr int NH = 4;       // heads
constexpr unsigned F32_ONE = 0x3F800000u;
// 1/sqrt(32) * log2(e): exp(l) = exp2(l*log2e), constants fused
constexpr float KC = 0.25503486f;

__device__ __forceinline__ float ldf(const void* p, int i, bool f32) {
    return f32 ? ((const float*)p)[i]
               : __bfloat162float(((const bf16*)p)[i]);
}

__device__ __forceinline__ int ld_idx(const void* p, long long i, bool i64) {
    return i64 ? (int)((const long long*)p)[i] : ((const int*)p)[i];
}

__device__ __forceinline__ bool probe_i64(const void* ei) {
    const unsigned* u = (const unsigned*)ei;
    return (u[1] | u[3] | u[5] | u[7]) == 0u;
}

// f32 -> bf16 bits (RNE)
__device__ __forceinline__ unsigned f2bu(float x) {
    unsigned u = __float_as_uint(x);
    return (u + 0x7FFFu + ((u >> 16) & 1u)) >> 16;
}

__device__ __forceinline__ h2 u2h(unsigned u) { return __builtin_bit_cast(h2, u); }

// dot2: c += a[0]*b[0] + a[1]*b[1] (f16 inputs, f32 accum)
__device__ __forceinline__ float fdot2(h2 a, h2 b, float c) {
#if __has_builtin(__builtin_amdgcn_fdot2)
    return __builtin_amdgcn_fdot2(a, b, c, false);
#else
    return c + (float)a[0] * (float)b[0] + (float)a[1] * (float)b[1];
#endif
}

__device__ __forceinline__ h2 relu2(h2 a) {
    h2 z = {(_Float16)0.f, (_Float16)0.f};
#if __has_builtin(__builtin_elementwise_max)
    return __builtin_elementwise_max(a, z);
#else
    h2 r;
    r[0] = a[0] > (_Float16)0.f ? a[0] : (_Float16)0.f;
    r[1] = a[1] > (_Float16)0.f ? a[1] : (_Float16)0.f;
    return r;
#endif
}

// DPP-based add of a lane-permuted copy (VALU pipe; NO ds_bpermute).
// ctrl: 0xB1 = quad_perm xor1, 0x4E = quad_perm xor2,
//       0x128 = row_ror:8 (== xor8 within 16-row), 0x124 = row_ror:4.
// Sequence xor1,xor2,ror8,ror4 = full 16-lane allreduce (all lanes get sum).
#define DPPADD(x, ctrl) \
    ((x) + __int_as_float(__builtin_amdgcn_mov_dpp(__float_as_int(x), (ctrl), 0xF, 0xF, false)))

// wave-uniform value -> SGPR (compiler can't prove threadIdx.x>>6 uniform)
__device__ __forceinline__ int rfl(int v) { return __builtin_amdgcn_readfirstlane(v); }

// ---- fp8 e4m3 helpers ------------------------------------------------------
__device__ __forceinline__ unsigned char f32_to_fp8(float x) {
#if __has_builtin(__builtin_amdgcn_cvt_pk_fp8_f32)
    return (unsigned char)(__builtin_amdgcn_cvt_pk_fp8_f32(x, x, 0, false) & 0xFF);
#else
    unsigned bits = __float_as_uint(x);
    unsigned s = bits >> 31;
    float a = fabsf(x);
    if (a >= 448.f) return (unsigned char)((s << 7) | 0x7E);
    if (a < 0.015625f) {
        int m = (int)(a * 512.f + 0.5f);
        if (m >= 8) return (unsigned char)((s << 7) | 0x08);
        return (unsigned char)((s << 7) | m);
    }
    unsigned ab = (bits & 0x7FFFFFFFu) + 0x00080000u;
    int e8 = (int)(ab >> 23) - 127 + 7;
    unsigned m3 = (ab >> 20) & 7u;
    if (e8 >= 16) return (unsigned char)((s << 7) | 0x7E);
    return (unsigned char)((s << 7) | ((unsigned)e8 << 3) | m3);
#endif
}

__device__ __forceinline__ void fp8x2_to_f32(unsigned u, float& f0, float& f1) {
#if __has_builtin(__builtin_amdgcn_cvt_pk_f32_fp8)
    f32x2 lo = __builtin_amdgcn_cvt_pk_f32_fp8(u, false);
    f0 = lo[0]; f1 = lo[1];
#else
    float r[2];
#pragma unroll
    for (int j = 0; j < 2; ++j) {
        unsigned b = (u >> (8 * j)) & 0xFF;
        unsigned s = b >> 7, e = (b >> 3) & 15, m = b & 7;
        float v = (e == 0) ? (float)m * 0.001953125f
                           : __uint_as_float(((e + 120u) << 23) | (m << 20));
        r[j] = s ? -v : v;
    }
    f0 = r[0]; f1 = r[1];
#endif
}

// ---------------------------------------------------------------------------
// prep: fused one-shot conversions + csr_count. (cnt/ssum zeroed by memset)
// bcat: [0,128)=bq, [128,256)=bk, [256,384)=bv, [384,512)=0 (a), [512,640)=be1 (b')
// We2h packing (for edge_gather's 16-lane scheme): entry t = lane*4 + k,
//   lane: g = lane>>4 (head), i = lane&15; pair index pp = 4*i + k;
//   value = half2( We2[2pp][g], We2[2pp+1][g] ).
// ---------------------------------------------------------------------------
constexpr int PB_X   = 12500;
constexpr int PB_W   = 160;
constexpr int PB_WO  = 64;
constexpr int PB_CNT = 3125;   // csr_count: NE/256

__global__ __launch_bounds__(256) void prep(
    const void* __restrict__ x,
    const void* __restrict__ Wq, const void* __restrict__ bq,
    const void* __restrict__ Wk, const void* __restrict__ bk,
    const void* __restrict__ Wv, const void* __restrict__ bv,
    const void* __restrict__ We1, const void* __restrict__ be1,
    const void* __restrict__ We2, const void* __restrict__ be2,
    const void* __restrict__ Wo,  const unsigned* __restrict__ gw,
    const void* __restrict__ eia, const void* __restrict__ eib, int split,
    bf16* __restrict__ xb, bf16* __restrict__ WcatT, bf16* __restrict__ WoT,
    int* __restrict__ cnt,
    unsigned* __restrict__ We2h, float* __restrict__ be2f,
    float* __restrict__ bcat)
{
    const bool f32 = (gw[0] == F32_ONE);
    int b = blockIdx.x, t = threadIdx.x;
    if (b < PB_X) {
        int i = b * 256 + t;
        if (i < NN * IC) xb[i] = __float2bfloat16(ldf(x, i, f32));
    } else if (b < PB_X + PB_W) {
        int idx = (b - PB_X) * 256 + t;         // n*64 + k
        int n = idx >> 6, k = idx & 63;
        int sel = n >> 7, c = n & 127;
        float v;
        if (sel == 0)      v = ldf(Wq, k * OC + c, f32);
        else if (sel == 1) v = ldf(Wk, k * OC + c, f32);
        else if (sel == 2) v = ldf(Wv, k * OC + c, f32);
        else if (sel == 3) v = ldf(We1, k * OC + c, f32);
        else               v = ldf(We1, (IC + k) * OC + c, f32);
        WcatT[idx] = __float2bfloat16(v);
    } else if (b < PB_X + PB_W + PB_WO) {
        int idx = (b - PB_X - PB_W) * 256 + t;  // n*128 + k
        int n = idx >> 7, k = idx & 127;
        WoT[idx] = __float2bfloat16(ldf(Wo, k * OC + n, f32));
    } else if (b < PB_X + PB_W + PB_WO + PB_CNT) {
        const bool i64 = probe_i64(eia);
        long long e = (long long)(b - PB_X - PB_W - PB_WO) * 256 + t;
        int d = split ? ld_idx(eib, e, i64) : ld_idx(eia, NE + e, i64);
        atomicAdd(&cnt[d], 1);
    } else {
        if (t < NH) be2f[t] = ldf(be2, t, f32);
        // We2h: 64 lanes x 4 dwords, per-lane 8-channel weight slice for ONE head
        {
            int ln = t >> 2, k = t & 3;         // t in [0,256)
            int g = ln >> 4, ii = ln & 15;
            int pp = 4 * ii + k;
            h2 hv;
            hv[0] = (_Float16)ldf(We2, (2 * pp) * NH + g, f32);
            hv[1] = (_Float16)ldf(We2, (2 * pp + 1) * NH + g, f32);
            We2h[t] = __builtin_bit_cast(unsigned, hv);
        }
        for (int n = t; n < 5 * OC; n += 256) {
            int sel = n >> 7, c = n & 127;
            float bb = 0.f;
            if (sel == 0) bb = ldf(bq, c, f32);
            else if (sel == 1) bb = ldf(bk, c, f32);
            else if (sel == 2) bb = ldf(bv, c, f32);
            else if (sel == 4) bb = ldf(be1, c, f32);  // fold be1 into b'
            bcat[n] = bb;
        }
    }
}

// ---------------------------------------------------------------------------
// Parallel CSR scan:
//   scan_part: 49 blocks x 1024 elems — block sums -> bsum[b]; rowptr[NN]=NE.
//   scan_fin : 49 blocks — wave0 reduces bsum[0..b), 64-lane shfl_up inclusive
//              scan + cross-wave LDS fixup, int4 stores of rowptr/cursor.
// ---------------------------------------------------------------------------
constexpr int SCAN_NB = 49;   // 49*1024 = 50176 >= NN; NN%4==0 so int4 ok

__global__ __launch_bounds__(256) void scan_part(const int* __restrict__ cnt,
                                                 int* __restrict__ bsum,
                                                 int* __restrict__ rowptr)
{
    int b = blockIdx.x, t = threadIdx.x;
    int base = b * 1024 + t * 4;
    int4 v;
    if (base < NN) v = *(const int4*)(cnt + base);
    else { v.x = 0; v.y = 0; v.z = 0; v.w = 0; }
    int s = v.x + v.y + v.z + v.w;
#pragma unroll
    for (int off = 1; off < 64; off <<= 1) s += __shfl_xor(s, off);
    __shared__ int sm[4];
    int lane = t & 63, w = t >> 6;
    if (lane == 0) sm[w] = s;
    __syncthreads();
    if (t == 0) bsum[b] = sm[0] + sm[1] + sm[2] + sm[3];
    if (b == 0 && t == 0) rowptr[NN] = NE;   // counts always sum to NE
}

__global__ __launch_bounds__(256) void scan_fin(const int* __restrict__ cnt,
                                                const int* __restrict__ bsum,
                                                int* __restrict__ rowptr,
                                                int* __restrict__ cursor)
{
    int b = blockIdx.x, t = threadIdx.x;
    int lane = t & 63, w = t >> 6;
    __shared__ int s_boff;
    __shared__ int wsum[4];
    if (w == 0) {
        int pre = (lane < b) ? bsum[lane] : 0;   // b <= 48 < 64
#pragma unroll
        for (int off = 1; off < 64; off <<= 1) pre += __shfl_xor(pre, off);
        if (lane == 0) s_boff = pre;
    }
    int base = b * 1024 + t * 4;
    int4 v;
    if (base < NN) v = *(const int4*)(cnt + base);
    else { v.x = 0; v.y = 0; v.z = 0; v.w = 0; }
    int s = v.x + v.y + v.z + v.w;
    int inc = s;
#pragma unroll
    for (int off = 1; off < 64; off <<= 1) {
        int u = __shfl_up(inc, off);
        if (lane >= off) inc += u;
    }
    if (lane == 63) wsum[w] = inc;
    __syncthreads();
    int run = s_boff + (inc - s);
#pragma unroll
    for (int i = 0; i < 3; ++i) if (i < w) run += wsum[i];
    if (base < NN) {
        int4 rp;
        rp.x = run;
        rp.y = rp.x + v.x;
        rp.z = rp.y + v.y;
        rp.w = rp.z + v.z;
        *(int4*)(rowptr + base) = rp;
        *(int4*)(cursor + base) = rp;
    }
}

// ---------------------------------------------------------------------------
// node_gemm (+fused csr_fill): blocks [0,3125) GEMM, [3125,6250) fill.
// GEMM: D[50000 x 640] = xb @ Wcat + bcat (MFMA).
// Outputs: qb_dst row (f16, 512B) = [q 128ch | b' 128ch];
//          ka_src row (f16, 512B) = [k 128ch | a 128ch]; vf8 row 128B (fp8).
// ---------------------------------------------------------------------------
constexpr int NG_GEMM = 3125;   // NN/16
constexpr int NG_FILL = 3125;   // NE/256

__global__ __launch_bounds__(256) void node_gemm(
    const bf16* __restrict__ xb, const bf16* __restrict__ WcatT,
    const float* __restrict__ bcat,
    unsigned char* __restrict__ qb_dst, unsigned char* __restrict__ ka_src,
    unsigned char* __restrict__ vf8,
    const void* __restrict__ eia, const void* __restrict__ eib, int split,
    int* __restrict__ cursor, int* __restrict__ ssrc)
{
    if (blockIdx.x >= NG_GEMM) {
        // ---- csr_fill ----
        const bool i64 = probe_i64(eia);
        long long e = (long long)(blockIdx.x - NG_GEMM) * 256 + threadIdx.x;
        int s = ld_idx(eia, e, i64);
        int d = split ? ld_idx(eib, e, i64) : ld_idx(eia, NE + e, i64);
        int pos = atomicAdd(&cursor[d], 1);
        ssrc[pos] = s;
        return;
    }
    int wave = threadIdx.x >> 6;
    int lane = threadIdx.x & 63;
    int quad = lane >> 4;
    int l16  = lane & 15;
    int row_base = blockIdx.x * 16;
    int m = row_base + l16;

    short8 a0 = *(const short8*)(xb + (size_t)m * IC + quad * 8);
    short8 a1 = *(const short8*)(xb + (size_t)m * IC + 32 + quad * 8);

    _Float16* qh = (_Float16*)qb_dst;
    _Float16* kh = (_Float16*)ka_src;

#pragma unroll
    for (int t = 0; t < 10; ++t) {
        int colbase = wave * 160 + t * 16;
        const bf16* bp = WcatT + (size_t)(colbase + l16) * IC + quad * 8;
        short8 b0 = *(const short8*)(bp);
        short8 b1 = *(const short8*)(bp + 32);
        f32x4 acc = {0.f, 0.f, 0.f, 0.f};
        acc = __builtin_amdgcn_mfma_f32_16x16x32_bf16(a0, b0, acc, 0, 0, 0);
        acc = __builtin_amdgcn_mfma_f32_16x16x32_bf16(a1, b1, acc, 0, 0, 0);

        float bias = bcat[colbase + l16];
        int sel = colbase >> 7;
        int cc  = (colbase & 127) + l16;
#pragma unroll
        for (int r = 0; r < 4; ++r) {
            int node = row_base + quad * 4 + r;
            float fv = acc[r] + bias;
            if (sel == 2) {
                vf8[(size_t)node * OC + cc] = f32_to_fp8(fv);
            } else {
                _Float16 val = (_Float16)fv;
                if (sel == 0)      qh[(size_t)node * 256 + cc] = val;
                else if (sel == 1) kh[(size_t)node * 256 + cc] = val;
                else if (sel == 3) kh[(size_t)node * 256 + 128 + cc] = val;
                else               qh[(size_t)node * 256 + 128 + cc] = val;
            }
        }
    }
}

// ---------------------------------------------------------------------------
// edge_gather: FUSED edge logit + softmax-weighted aggregation, 2-edge ILP.
// 16-lane-partition + DPP allreduce (zero LDS-pipe ops); this round: ALL
// wave-uniform values (beg/end, every ssrc index) forced to SGPRs via
// readfirstlane -> row-base addressing and loop control move to the scalar
// pipe, vector loads become [SGPR base + loop-invariant lane offset], and
// ssrc reads become s_load. Cuts ~30% of VALU issue.
// ---------------------------------------------------------------------------
__global__ __launch_bounds__(256) void edge_gather(
    const int* __restrict__ rowptr, const int* __restrict__ ssrc,
    unsigned char* __restrict__ qb_dst, const unsigned char* __restrict__ ka_src,
    const unsigned char* __restrict__ vf8,
    const unsigned* __restrict__ We2h, const float* __restrict__ be2f,
    float* __restrict__ spart)
{
    int node = rfl(blockIdx.x * 4 + (threadIdx.x >> 6));
    int lane = threadIdx.x & 63;
    int i16  = lane & 15;
    int myh  = lane >> 4;

    // dst-row data: q pair for t, b' 8ch for gate
    const unsigned char* drow = qb_dst + (size_t)node * 512;
    h2 dq = u2h(*(const unsigned*)(drow + lane * 4));
    uint4 dbu = *(const uint4*)(drow + 256 + 16 * i16);
    h2 db0 = u2h(dbu.x), db1 = u2h(dbu.y), db2 = u2h(dbu.z), db3 = u2h(dbu.w);

    // gate weights for this lane's 8 channels, head myh
    uint4 wu = *(const uint4*)(We2h + lane * 4);
    h2 w0 = u2h(wu.x), w1 = u2h(wu.y), w2 = u2h(wu.z), w3 = u2h(wu.w);
    float be2h = be2f[myh];

    int beg = rfl(rowptr[node]);
    int end = rfl(rowptr[node + 1]);
    float o0 = 0.f, o1 = 0.f, s_acc = 0.f;

    if (beg < end) {
        int ib = (beg + 1 < end) ? beg + 1 : end - 1;
        int sa = rfl(ssrc[beg]);
        int sb = rfl(ssrc[ib]);
        const unsigned char* ra = ka_src + (size_t)sa * 512;
        const unsigned char* rb = ka_src + (size_t)sb * 512;
        unsigned kuA = *(const unsigned*)(ra + lane * 4);
        uint4    auA = *(const uint4*)(ra + 256 + 16 * i16);
        unsigned uvA = *(const unsigned short*)(vf8 + (size_t)sa * OC + 2 * lane);
        unsigned kuB = *(const unsigned*)(rb + lane * 4);
        uint4    auB = *(const uint4*)(rb + 256 + 16 * i16);
        unsigned uvB = *(const unsigned short*)(vf8 + (size_t)sb * OC + 2 * lane);
        int na = (beg + 2 < end) ? beg + 2 : end - 1;
        int nb = (beg + 3 < end) ? beg + 3 : end - 1;
        int sna = rfl(ssrc[na]);
        int snb = rfl(ssrc[nb]);

        for (int p = beg; p < end; p += 2) {
            // issue next-pair row loads (indices already resident, SGPR bases)
            const unsigned char* rc = ka_src + (size_t)sna * 512;
            const unsigned char* rd = ka_src + (size_t)snb * 512;
            unsigned kuC = *(const unsigned*)(rc + lane * 4);
            uint4    auC = *(const uint4*)(rc + 256 + 16 * i16);
            unsigned uvC = *(const unsigned short*)(vf8 + (size_t)sna * OC + 2 * lane);
            unsigned kuD = *(const unsigned*)(rd + lane * 4);
            uint4    auD = *(const uint4*)(rd + 256 + 16 * i16);
            unsigned uvD = *(const unsigned short*)(vf8 + (size_t)snb * OC + 2 * lane);
            // indices for pair p+4 (consumed next iteration) — scalar loads
            int fa = (p + 4 < end) ? p + 4 : end - 1;
            int fb = (p + 5 < end) ? p + 5 : end - 1;
            int s4a = rfl(ssrc[fa]);
            int s4b = rfl(ssrc[fb]);

            bool hasB = (p + 1 < end);

            // t partials (2 ch each)
            float tA = fdot2(u2h(kuA), dq, 0.f);
            float tB = fdot2(u2h(kuB), dq, 0.f);
            // gate partials (8 ch each, head myh)
            h2 hA0 = relu2(u2h(auA.x) + db0);
            h2 hA1 = relu2(u2h(auA.y) + db1);
            h2 hA2 = relu2(u2h(auA.z) + db2);
            h2 hA3 = relu2(u2h(auA.w) + db3);
            h2 hB0 = relu2(u2h(auB.x) + db0);
            h2 hB1 = relu2(u2h(auB.y) + db1);
            h2 hB2 = relu2(u2h(auB.z) + db2);
            h2 hB3 = relu2(u2h(auB.w) + db3);
            float pA = fdot2(hA3, w3, fdot2(hA2, w2, fdot2(hA1, w1, fdot2(hA0, w0, 0.f))));
            float pB = fdot2(hB3, w3, fdot2(hB2, w2, fdot2(hB1, w1, fdot2(hB0, w0, 0.f))));

            // 16-lane DPP allreduce (both scalars, interleaved for ILP)
            tA = DPPADD(tA, 0xB1);  pA = DPPADD(pA, 0xB1);
            tB = DPPADD(tB, 0xB1);  pB = DPPADD(pB, 0xB1);
            tA = DPPADD(tA, 0x4E);  pA = DPPADD(pA, 0x4E);
            tB = DPPADD(tB, 0x4E);  pB = DPPADD(pB, 0x4E);
            tA = DPPADD(tA, 0x128); pA = DPPADD(pA, 0x128);
            tB = DPPADD(tB, 0x128); pB = DPPADD(pB, 0x128);
            tA = DPPADD(tA, 0x124); pA = DPPADD(pA, 0x124);
            tB = DPPADD(tB, 0x124); pB = DPPADD(pB, 0x124);

            float coefA = exp2f(tA * (pA + be2h) * KC);
            float coefB = hasB ? exp2f(tB * (pB + be2h) * KC) : 0.f;
            s_acc += coefA + coefB;

            float vA0, vA1, vB0, vB1;
            fp8x2_to_f32(uvA, vA0, vA1);
            fp8x2_to_f32(uvB, vB0, vB1);
            o0 = fmaf(coefA, vA0, fmaf(coefB, vB0, o0));
            o1 = fmaf(coefA, vA1, fmaf(coefB, vB1, o1));

            kuA = kuC; auA = auC; uvA = uvC;
            kuB = kuD; auB = auD; uvB = uvD;
            sna = s4a; snb = s4b;
        }
    }
    // write agg row (bf16, 256B) into first half of this node's qb row
    *(unsigned*)(qb_dst + (size_t)node * 512 + lane * 4) = f2bu(o0) | (f2bu(o1) << 16);
    if (i16 == 0) spart[node * 4 + myh] = s_acc;
}

// ---------------------------------------------------------------------------
// s_reduce: PARALLEL reduction of spart (NN*4) -> ssum[4] via atomics.
// ---------------------------------------------------------------------------
constexpr int SR_BLOCKS = 98;
__global__ __launch_bounds__(256) void s_reduce(const float* __restrict__ spart,
                                                float* __restrict__ ssum)
{
    int tid = blockIdx.x * 256 + threadIdx.x;
    int h = threadIdx.x & 3;
    float s = 0.f;
    for (int i = tid; i < NN * 4; i += SR_BLOCKS * 256) s += spart[i];
#pragma unroll
    for (int off = 4; off <= 32; off <<= 1) s += __shfl_xor(s, off);
    __shared__ float sm[4][4];
    int lane = threadIdx.x & 63, w = threadIdx.x >> 6;
    if (lane < 4) sm[w][h] = s;
    __syncthreads();
    if (threadIdx.x < 4) {
        float tot = sm[0][h] + sm[1][h] + sm[2][h] + sm[3][h];
        atomicAdd(&ssum[h], tot);
    }
}

// ---------------------------------------------------------------------------
// out_gemm: MFMA out GEMM + fused softmax-normalization + fused LN.
// Agg rows live at stride 512 B inside qb_dst (first half of each row).
// ---------------------------------------------------------------------------
__global__ __launch_bounds__(256) void out_gemm(
    const unsigned char* __restrict__ aggv, const bf16* __restrict__ WoT,
    const void* __restrict__ bo, const void* __restrict__ gamma,
    const void* __restrict__ beta, const unsigned* __restrict__ gw,
    const float* __restrict__ ssum,
    void* __restrict__ out)
{
    const bool f32 = (gw[0] == F32_ONE);
    int wave = threadIdx.x >> 6;
    int lane = threadIdx.x & 63;
    int quad = lane >> 4;
    int l16  = lane & 15;
    int rb = blockIdx.x * 64 + wave * 16;
    int m = rb + l16;
    int ma = (m < NN) ? m : 0;

    const bf16* arow = (const bf16*)(aggv + (size_t)ma * 512);
    short8 a[4];
#pragma unroll
    for (int h = 0; h < 4; ++h) {
        short8 raw = *(const short8*)(arow + h * 32 + quad * 8);
        float invh = 1.0f / ssum[h];
#pragma unroll
        for (int jj = 0; jj < 8; ++jj) {
            float f = __uint_as_float(((unsigned)(unsigned short)raw[jj]) << 16) * invh;
            raw[jj] = (short)f2bu(f);
        }
        a[h] = raw;
    }

    float o[8][4];
#pragma unroll
    for (int t = 0; t < 8; ++t) {
        const bf16* bp = WoT + (size_t)(t * 16 + l16) * OC + quad * 8;
        f32x4 acc = {0.f, 0.f, 0.f, 0.f};
#pragma unroll
        for (int h = 0; h < 4; ++h) {
            short8 bfr = *(const short8*)(bp + h * 32);
            acc = __builtin_amdgcn_mfma_f32_16x16x32_bf16(a[h], bfr, acc, 0, 0, 0);
        }
        float bias = ldf(bo, t * 16 + l16, f32);
#pragma unroll
        for (int r = 0; r < 4; ++r) o[t][r] = acc[r] + bias;
    }

#pragma unroll
    for (int r = 0; r < 4; ++r) {
        float s1 = 0.f, s2 = 0.f;
#pragma unroll
        for (int t = 0; t < 8; ++t) { s1 += o[t][r]; s2 += o[t][r] * o[t][r]; }
#pragma unroll
        for (int off = 1; off <= 8; off <<= 1) {
            s1 += __shfl_xor(s1, off);
            s2 += __shfl_xor(s2, off);
        }
        float mu = s1 * (1.0f / OC);
        float var = fmaxf(s2 * (1.0f / OC) - mu * mu, 0.f);
        float rs = rsqrtf(var + 1e-5f);
        int node = rb + quad * 4 + r;
        if (node < NN) {
#pragma unroll
            for (int t = 0; t < 8; ++t) {
                int col = t * 16 + l16;
                float y = (o[t][r] - mu) * rs * ldf(gamma, col, f32) + ldf(beta, col, f32);
                if (f32) ((float*)out)[(size_t)node * OC + col] = y;
                else     ((bf16*)out)[(size_t)node * OC + col] = __float2bfloat16(y);
            }
        }
    }
}

// ---------------------------------------------------------------------------
extern "C" void kernel_launch(void* const* d_in, const int* in_sizes, int n_in,
                              void* d_out, int out_size, void* d_ws, size_t ws_size,
                              hipStream_t stream)
{
    int p = 0;
    const void* x   = d_in[p++];
    const void* eia = d_in[p++];
    const void* eib = eia;
    int split = 0;
    if (n_in >= 17) { eib = d_in[p++]; split = 1; }
    const void* Wq   = d_in[p++];
    const void* bq   = d_in[p++];
    const void* Wk   = d_in[p++];
    const void* bk   = d_in[p++];
    const void* Wv   = d_in[p++];
    const void* bv   = d_in[p++];
    const void* We1  = d_in[p++];
    const void* be1  = d_in[p++];
    const void* We2  = d_in[p++];
    const void* be2  = d_in[p++];
    const void* Wo   = d_in[p++];
    const void* bo   = d_in[p++];
    const void* gamma= d_in[p++];
    const void* beta = d_in[p++];
    const unsigned* gw = (const unsigned*)gamma;

    // workspace layout (~69 MB). cnt and ssum adjacent -> single memset.
    char* w = (char*)d_ws;
    bf16*  xb     = (bf16*)w;                  w += (size_t)NN * IC * 2;  // 6.4 MB
    unsigned char* qb_dst = (unsigned char*)w; w += (size_t)NN * 512;     // 25.6 MB (f16 q|b')
    unsigned char* ka_src = (unsigned char*)w; w += (size_t)NN * 512;     // 25.6 MB (f16 k|a)
    unsigned char* vf8    = (unsigned char*)w; w += (size_t)NN * OC;      // 6.4 MB
    int*   ssrc   = (int*)w;                   w += (size_t)NE * 4;       // 3.2 MB
    int*   cnt    = (int*)w;                   w += (size_t)NN * 4;       // 200 KB
    float* ssum   = (float*)w;                 w += 8 * 4;                // (memset w/ cnt)
    int*   rowptr = (int*)w;                   w += (size_t)(NN + 4) * 4; // padded to 16B
    int*   cursor = (int*)w;                   w += (size_t)NN * 4;
    int*   bsum   = (int*)w;                   w += 64 * 4;               // scan block sums
    float* spart  = (float*)w;                 w += (size_t)NN * 4 * 4;   // 800 KB
    unsigned* We2h = (unsigned*)w;             w += 256 * 4;              // 1 KB
    float* be2f   = (float*)w;                 w += NH * 4;
    bf16*  WcatT  = (bf16*)w;                  w += (size_t)5 * OC * IC * 2;
    float* bcat   = (float*)w;                 w += 5 * OC * 4;
    bf16*  WoT    = (bf16*)w;                  w += (size_t)OC * OC * 2;

    if (ws_size < (size_t)((char*)w - (char*)d_ws)) return;

    hipMemsetAsync(cnt, 0, (size_t)NN * 4 + 32, stream);   // cnt + ssum
    prep<<<PB_X + PB_W + PB_WO + PB_CNT + 1, 256, 0, stream>>>(
        x, Wq, bq, Wk, bk, Wv, bv, We1, be1, We2, be2, Wo, gw,
        eia, eib, split,
        xb, WcatT, WoT, cnt, We2h, be2f, bcat);
    scan_part<<<SCAN_NB, 256, 0, stream>>>(cnt, bsum, rowptr);
    scan_fin<<<SCAN_NB, 256, 0, stream>>>(cnt, bsum, rowptr, cursor);
    node_gemm<<<NG_GEMM + NG_FILL, 256, 0, stream>>>(
        xb, WcatT, bcat, qb_dst, ka_src, vf8, eia, eib, split, cursor, ssrc);
    edge_gather<<<NN / 4, 256, 0, stream>>>(rowptr, ssrc, qb_dst, ka_src, vf8,
                                            We2h, be2f, spart);
    s_reduce<<<SR_BLOCKS, 256, 0, stream>>>(spart, ssum);
    out_gemm<<<(NN + 63) / 64, 256, 0, stream>>>(qb_dst, WoT, bo, gamma, beta, gw,
                                                 ssum, d_out);
}

// Round 4
// 291.901 us; speedup vs baseline: 1.7648x; 1.1050x over previous
//
#include <hip/hip_runtime.h>
#include <hip/hip_bf16.h>

typedef __hip_bfloat16 bf16;
typedef __attribute__((ext_vector_type(8))) short short8;   // 8 bf16 (4 VGPRs)
typedef __attribute__((ext_vector_type(4))) float f32x4;    // 4 fp32 acc
typedef __attribute__((ext_vector_type(2))) float f32x2;
typedef _Float16 h2 __attribute__((ext_vector_type(2)));    // packed half2

constexpr int NN = 50000;   // nodes
constexpr int NE = 800000;  // edges
constexpr int IC = 64;      // in channels
constexpr int OC = 128;     // out channels
constexpr int NH = 4;       // heads
constexpr unsigned F32_ONE = 0x3F800000u;
// 1/sqrt(32) * log2(e): exp(l) = exp2(l*log2e), constants fused
constexpr float KC = 0.25503486f;

__device__ __forceinline__ float ldf(const void* p, int i, bool f32) {
    return f32 ? ((const float*)p)[i]
               : __bfloat162float(((const bf16*)p)[i]);
}

__device__ __forceinline__ int ld_idx(const void* p, long long i, bool i64) {
    return i64 ? (int)((const long long*)p)[i] : ((const int*)p)[i];
}

__device__ __forceinline__ bool probe_i64(const void* ei) {
    const unsigned* u = (const unsigned*)ei;
    return (u[1] | u[3] | u[5] | u[7]) == 0u;
}

// f32 -> bf16 bits (RNE)
__device__ __forceinline__ unsigned f2bu(float x) {
    unsigned u = __float_as_uint(x);
    return (u + 0x7FFFu + ((u >> 16) & 1u)) >> 16;
}

__device__ __forceinline__ h2 u2h(unsigned u) { return __builtin_bit_cast(h2, u); }

// dot2: c += a[0]*b[0] + a[1]*b[1] (f16 inputs, f32 accum)
__device__ __forceinline__ float fdot2(h2 a, h2 b, float c) {
#if __has_builtin(__builtin_amdgcn_fdot2)
    return __builtin_amdgcn_fdot2(a, b, c, false);
#else
    return c + (float)a[0] * (float)b[0] + (float)a[1] * (float)b[1];
#endif
}

__device__ __forceinline__ h2 relu2(h2 a) {
    h2 z = {(_Float16)0.f, (_Float16)0.f};
#if __has_builtin(__builtin_elementwise_max)
    return __builtin_elementwise_max(a, z);
#else
    h2 r;
    r[0] = a[0] > (_Float16)0.f ? a[0] : (_Float16)0.f;
    r[1] = a[1] > (_Float16)0.f ? a[1] : (_Float16)0.f;
    return r;
#endif
}

// DPP-based add of a lane-permuted copy (VALU pipe; NO ds_bpermute).
// ctrl: 0xB1 = quad_perm xor1, 0x4E = quad_perm xor2,
//       0x128 = row_ror:8 (== xor8 within 16-row), 0x124 = row_ror:4.
// Sequence xor1,xor2,ror8,ror4 = full 16-lane allreduce (all lanes get sum).
#define DPPADD(x, ctrl) \
    ((x) + __int_as_float(__builtin_amdgcn_mov_dpp(__float_as_int(x), (ctrl), 0xF, 0xF, false)))

// wave-uniform value -> SGPR (compiler can't prove threadIdx.x>>6 uniform)
__device__ __forceinline__ int rfl(int v) { return __builtin_amdgcn_readfirstlane(v); }

// ---- fp8 e4m3 helpers ------------------------------------------------------
__device__ __forceinline__ unsigned char f32_to_fp8(float x) {
#if __has_builtin(__builtin_amdgcn_cvt_pk_fp8_f32)
    return (unsigned char)(__builtin_amdgcn_cvt_pk_fp8_f32(x, x, 0, false) & 0xFF);
#else
    unsigned bits = __float_as_uint(x);
    unsigned s = bits >> 31;
    float a = fabsf(x);
    if (a >= 448.f) return (unsigned char)((s << 7) | 0x7E);
    if (a < 0.015625f) {
        int m = (int)(a * 512.f + 0.5f);
        if (m >= 8) return (unsigned char)((s << 7) | 0x08);
        return (unsigned char)((s << 7) | m);
    }
    unsigned ab = (bits & 0x7FFFFFFFu) + 0x00080000u;
    int e8 = (int)(ab >> 23) - 127 + 7;
    unsigned m3 = (ab >> 20) & 7u;
    if (e8 >= 16) return (unsigned char)((s << 7) | 0x7E);
    return (unsigned char)((s << 7) | ((unsigned)e8 << 3) | m3);
#endif
}

__device__ __forceinline__ void fp8x2_to_f32(unsigned u, float& f0, float& f1) {
#if __has_builtin(__builtin_amdgcn_cvt_pk_f32_fp8)
    f32x2 lo = __builtin_amdgcn_cvt_pk_f32_fp8(u, false);
    f0 = lo[0]; f1 = lo[1];
#else
    float r[2];
#pragma unroll
    for (int j = 0; j < 2; ++j) {
        unsigned b = (u >> (8 * j)) & 0xFF;
        unsigned s = b >> 7, e = (b >> 3) & 15, m = b & 7;
        float v = (e == 0) ? (float)m * 0.001953125f
                           : __uint_as_float(((e + 120u) << 23) | (m << 20));
        r[j] = s ? -v : v;
    }
    f0 = r[0]; f1 = r[1];
#endif
}

// ---------------------------------------------------------------------------
// prep: fused one-shot conversions + csr_count. (cnt/ssum zeroed by memset)
// The counting atomicAdd's RETURN VALUE is each edge's rank within its dst
// bucket -> stored to rank[e] (coalesced). csr_fill then needs NO atomics:
// pos = rowptr[d] + rank[e].
// bcat: [0,128)=bq, [128,256)=bk, [256,384)=bv, [384,512)=0 (a), [512,640)=be1 (b')
// ---------------------------------------------------------------------------
constexpr int PB_X   = 12500;
constexpr int PB_W   = 160;
constexpr int PB_WO  = 64;
constexpr int PB_CNT = 3125;   // csr_count: NE/256

__global__ __launch_bounds__(256) void prep(
    const void* __restrict__ x,
    const void* __restrict__ Wq, const void* __restrict__ bq,
    const void* __restrict__ Wk, const void* __restrict__ bk,
    const void* __restrict__ Wv, const void* __restrict__ bv,
    const void* __restrict__ We1, const void* __restrict__ be1,
    const void* __restrict__ We2, const void* __restrict__ be2,
    const void* __restrict__ Wo,  const unsigned* __restrict__ gw,
    const void* __restrict__ eia, const void* __restrict__ eib, int split,
    bf16* __restrict__ xb, bf16* __restrict__ WcatT, bf16* __restrict__ WoT,
    int* __restrict__ cnt, int* __restrict__ rank,
    unsigned* __restrict__ We2h, float* __restrict__ be2f,
    float* __restrict__ bcat)
{
    const bool f32 = (gw[0] == F32_ONE);
    int b = blockIdx.x, t = threadIdx.x;
    if (b < PB_X) {
        int i = b * 256 + t;
        if (i < NN * IC) xb[i] = __float2bfloat16(ldf(x, i, f32));
    } else if (b < PB_X + PB_W) {
        int idx = (b - PB_X) * 256 + t;         // n*64 + k
        int n = idx >> 6, k = idx & 63;
        int sel = n >> 7, c = n & 127;
        float v;
        if (sel == 0)      v = ldf(Wq, k * OC + c, f32);
        else if (sel == 1) v = ldf(Wk, k * OC + c, f32);
        else if (sel == 2) v = ldf(Wv, k * OC + c, f32);
        else if (sel == 3) v = ldf(We1, k * OC + c, f32);
        else               v = ldf(We1, (IC + k) * OC + c, f32);
        WcatT[idx] = __float2bfloat16(v);
    } else if (b < PB_X + PB_W + PB_WO) {
        int idx = (b - PB_X - PB_W) * 256 + t;  // n*128 + k
        int n = idx >> 7, k = idx & 127;
        WoT[idx] = __float2bfloat16(ldf(Wo, k * OC + n, f32));
    } else if (b < PB_X + PB_W + PB_WO + PB_CNT) {
        const bool i64 = probe_i64(eia);
        long long e = (long long)(b - PB_X - PB_W - PB_WO) * 256 + t;
        int d = split ? ld_idx(eib, e, i64) : ld_idx(eia, NE + e, i64);
        int r = atomicAdd(&cnt[d], 1);
        rank[e] = r;
    } else {
        if (t < NH) be2f[t] = ldf(be2, t, f32);
        // We2h: 64 lanes x 4 dwords, per-lane 8-channel weight slice for ONE head
        {
            int ln = t >> 2, k = t & 3;         // t in [0,256)
            int g = ln >> 4, ii = ln & 15;
            int pp = 4 * ii + k;
            h2 hv;
            hv[0] = (_Float16)ldf(We2, (2 * pp) * NH + g, f32);
            hv[1] = (_Float16)ldf(We2, (2 * pp + 1) * NH + g, f32);
            We2h[t] = __builtin_bit_cast(unsigned, hv);
        }
        for (int n = t; n < 5 * OC; n += 256) {
            int sel = n >> 7, c = n & 127;
            float bb = 0.f;
            if (sel == 0) bb = ldf(bq, c, f32);
            else if (sel == 1) bb = ldf(bk, c, f32);
            else if (sel == 2) bb = ldf(bv, c, f32);
            else if (sel == 4) bb = ldf(be1, c, f32);  // fold be1 into b'
            bcat[n] = bb;
        }
    }
}

// ---------------------------------------------------------------------------
// Parallel CSR scan:
//   scan_part: 49 blocks x 1024 elems — block sums -> bsum[b]; rowptr[NN]=NE.
//   scan_fin : 49 blocks — wave0 reduces bsum[0..b), 64-lane shfl_up inclusive
//              scan + cross-wave LDS fixup, int4 stores of rowptr.
// ---------------------------------------------------------------------------
constexpr int SCAN_NB = 49;   // 49*1024 = 50176 >= NN; NN%4==0 so int4 ok

__global__ __launch_bounds__(256) void scan_part(const int* __restrict__ cnt,
                                                 int* __restrict__ bsum,
                                                 int* __restrict__ rowptr)
{
    int b = blockIdx.x, t = threadIdx.x;
    int base = b * 1024 + t * 4;
    int4 v;
    if (base < NN) v = *(const int4*)(cnt + base);
    else { v.x = 0; v.y = 0; v.z = 0; v.w = 0; }
    int s = v.x + v.y + v.z + v.w;
#pragma unroll
    for (int off = 1; off < 64; off <<= 1) s += __shfl_xor(s, off);
    __shared__ int sm[4];
    int lane = t & 63, w = t >> 6;
    if (lane == 0) sm[w] = s;
    __syncthreads();
    if (t == 0) bsum[b] = sm[0] + sm[1] + sm[2] + sm[3];
    if (b == 0 && t == 0) rowptr[NN] = NE;   // counts always sum to NE
}

__global__ __launch_bounds__(256) void scan_fin(const int* __restrict__ cnt,
                                                const int* __restrict__ bsum,
                                                int* __restrict__ rowptr)
{
    int b = blockIdx.x, t = threadIdx.x;
    int lane = t & 63, w = t >> 6;
    __shared__ int s_boff;
    __shared__ int wsum[4];
    if (w == 0) {
        int pre = (lane < b) ? bsum[lane] : 0;   // b <= 48 < 64
#pragma unroll
        for (int off = 1; off < 64; off <<= 1) pre += __shfl_xor(pre, off);
        if (lane == 0) s_boff = pre;
    }
    int base = b * 1024 + t * 4;
    int4 v;
    if (base < NN) v = *(const int4*)(cnt + base);
    else { v.x = 0; v.y = 0; v.z = 0; v.w = 0; }
    int s = v.x + v.y + v.z + v.w;
    int inc = s;
#pragma unroll
    for (int off = 1; off < 64; off <<= 1) {
        int u = __shfl_up(inc, off);
        if (lane >= off) inc += u;
    }
    if (lane == 63) wsum[w] = inc;
    __syncthreads();
    int run = s_boff + (inc - s);
#pragma unroll
    for (int i = 0; i < 3; ++i) if (i < w) run += wsum[i];
    if (base < NN) {
        int4 rp;
        rp.x = run;
        rp.y = rp.x + v.x;
        rp.z = rp.y + v.y;
        rp.w = rp.z + v.z;
        *(int4*)(rowptr + base) = rp;
    }
}

// ---------------------------------------------------------------------------
// node_gemm (+fused csr_fill): blocks [0,3125) GEMM, [3125,6250) fill.
// GEMM: D[50000 x 640] = xb @ Wcat + bcat (MFMA).
// csr_fill is ATOMIC-FREE now: pos = rowptr[d] + rank[e] (rank captured from
// the counting atomic in prep). Pure coalesced loads + one scatter store.
// Outputs: qb_dst row (f16, 512B) = [q 128ch | b' 128ch];
//          ka_src row (f16, 512B) = [k 128ch | a 128ch]; vf8 row 128B (fp8).
// ---------------------------------------------------------------------------
constexpr int NG_GEMM = 3125;   // NN/16
constexpr int NG_FILL = 3125;   // NE/256

__global__ __launch_bounds__(256) void node_gemm(
    const bf16* __restrict__ xb, const bf16* __restrict__ WcatT,
    const float* __restrict__ bcat,
    unsigned char* __restrict__ qb_dst, unsigned char* __restrict__ ka_src,
    unsigned char* __restrict__ vf8,
    const void* __restrict__ eia, const void* __restrict__ eib, int split,
    const int* __restrict__ rowptr, const int* __restrict__ rank,
    int* __restrict__ ssrc)
{
    if (blockIdx.x >= NG_GEMM) {
        // ---- csr_fill (atomic-free) ----
        const bool i64 = probe_i64(eia);
        long long e = (long long)(blockIdx.x - NG_GEMM) * 256 + threadIdx.x;
        int s = ld_idx(eia, e, i64);
        int d = split ? ld_idx(eib, e, i64) : ld_idx(eia, NE + e, i64);
        int pos = rowptr[d] + rank[e];
        ssrc[pos] = s;
        return;
    }
    int wave = threadIdx.x >> 6;
    int lane = threadIdx.x & 63;
    int quad = lane >> 4;
    int l16  = lane & 15;
    int row_base = blockIdx.x * 16;
    int m = row_base + l16;

    short8 a0 = *(const short8*)(xb + (size_t)m * IC + quad * 8);
    short8 a1 = *(const short8*)(xb + (size_t)m * IC + 32 + quad * 8);

    _Float16* qh = (_Float16*)qb_dst;
    _Float16* kh = (_Float16*)ka_src;

#pragma unroll
    for (int t = 0; t < 10; ++t) {
        int colbase = wave * 160 + t * 16;
        const bf16* bp = WcatT + (size_t)(colbase + l16) * IC + quad * 8;
        short8 b0 = *(const short8*)(bp);
        short8 b1 = *(const short8*)(bp + 32);
        f32x4 acc = {0.f, 0.f, 0.f, 0.f};
        acc = __builtin_amdgcn_mfma_f32_16x16x32_bf16(a0, b0, acc, 0, 0, 0);
        acc = __builtin_amdgcn_mfma_f32_16x16x32_bf16(a1, b1, acc, 0, 0, 0);

        float bias = bcat[colbase + l16];
        int sel = colbase >> 7;
        int cc  = (colbase & 127) + l16;
#pragma unroll
        for (int r = 0; r < 4; ++r) {
            int node = row_base + quad * 4 + r;
            float fv = acc[r] + bias;
            if (sel == 2) {
                vf8[(size_t)node * OC + cc] = f32_to_fp8(fv);
            } else {
                _Float16 val = (_Float16)fv;
                if (sel == 0)      qh[(size_t)node * 256 + cc] = val;
                else if (sel == 1) kh[(size_t)node * 256 + cc] = val;
                else if (sel == 3) kh[(size_t)node * 256 + 128 + cc] = val;
                else               qh[(size_t)node * 256 + 128 + cc] = val;
            }
        }
    }
}

// ---------------------------------------------------------------------------
// edge_gather: FUSED edge logit + softmax-weighted aggregation, 2-edge ILP.
// 16-lane-partition + DPP allreduce (zero LDS-pipe ops); wave-uniform values
// (beg/end, every ssrc index) forced to SGPRs via readfirstlane.
// ---------------------------------------------------------------------------
__global__ __launch_bounds__(256) void edge_gather(
    const int* __restrict__ rowptr, const int* __restrict__ ssrc,
    unsigned char* __restrict__ qb_dst, const unsigned char* __restrict__ ka_src,
    const unsigned char* __restrict__ vf8,
    const unsigned* __restrict__ We2h, const float* __restrict__ be2f,
    float* __restrict__ spart)
{
    int node = rfl(blockIdx.x * 4 + (threadIdx.x >> 6));
    int lane = threadIdx.x & 63;
    int i16  = lane & 15;
    int myh  = lane >> 4;

    // dst-row data: q pair for t, b' 8ch for gate
    const unsigned char* drow = qb_dst + (size_t)node * 512;
    h2 dq = u2h(*(const unsigned*)(drow + lane * 4));
    uint4 dbu = *(const uint4*)(drow + 256 + 16 * i16);
    h2 db0 = u2h(dbu.x), db1 = u2h(dbu.y), db2 = u2h(dbu.z), db3 = u2h(dbu.w);

    // gate weights for this lane's 8 channels, head myh
    uint4 wu = *(const uint4*)(We2h + lane * 4);
    h2 w0 = u2h(wu.x), w1 = u2h(wu.y), w2 = u2h(wu.z), w3 = u2h(wu.w);
    float be2h = be2f[myh];

    int beg = rfl(rowptr[node]);
    int end = rfl(rowptr[node + 1]);
    float o0 = 0.f, o1 = 0.f, s_acc = 0.f;

    if (beg < end) {
        int ib = (beg + 1 < end) ? beg + 1 : end - 1;
        int sa = rfl(ssrc[beg]);
        int sb = rfl(ssrc[ib]);
        const unsigned char* ra = ka_src + (size_t)sa * 512;
        const unsigned char* rb = ka_src + (size_t)sb * 512;
        unsigned kuA = *(const unsigned*)(ra + lane * 4);
        uint4    auA = *(const uint4*)(ra + 256 + 16 * i16);
        unsigned uvA = *(const unsigned short*)(vf8 + (size_t)sa * OC + 2 * lane);
        unsigned kuB = *(const unsigned*)(rb + lane * 4);
        uint4    auB = *(const uint4*)(rb + 256 + 16 * i16);
        unsigned uvB = *(const unsigned short*)(vf8 + (size_t)sb * OC + 2 * lane);
        int na = (beg + 2 < end) ? beg + 2 : end - 1;
        int nb = (beg + 3 < end) ? beg + 3 : end - 1;
        int sna = rfl(ssrc[na]);
        int snb = rfl(ssrc[nb]);

        for (int p = beg; p < end; p += 2) {
            // issue next-pair row loads (indices already resident, SGPR bases)
            const unsigned char* rc = ka_src + (size_t)sna * 512;
            const unsigned char* rd = ka_src + (size_t)snb * 512;
            unsigned kuC = *(const unsigned*)(rc + lane * 4);
            uint4    auC = *(const uint4*)(rc + 256 + 16 * i16);
            unsigned uvC = *(const unsigned short*)(vf8 + (size_t)sna * OC + 2 * lane);
            unsigned kuD = *(const unsigned*)(rd + lane * 4);
            uint4    auD = *(const uint4*)(rd + 256 + 16 * i16);
            unsigned uvD = *(const unsigned short*)(vf8 + (size_t)snb * OC + 2 * lane);
            // indices for pair p+4 (consumed next iteration) — scalar loads
            int fa = (p + 4 < end) ? p + 4 : end - 1;
            int fb = (p + 5 < end) ? p + 5 : end - 1;
            int s4a = rfl(ssrc[fa]);
            int s4b = rfl(ssrc[fb]);

            bool hasB = (p + 1 < end);

            // t partials (2 ch each)
            float tA = fdot2(u2h(kuA), dq, 0.f);
            float tB = fdot2(u2h(kuB), dq, 0.f);
            // gate partials (8 ch each, head myh)
            h2 hA0 = relu2(u2h(auA.x) + db0);
            h2 hA1 = relu2(u2h(auA.y) + db1);
            h2 hA2 = relu2(u2h(auA.z) + db2);
            h2 hA3 = relu2(u2h(auA.w) + db3);
            h2 hB0 = relu2(u2h(auB.x) + db0);
            h2 hB1 = relu2(u2h(auB.y) + db1);
            h2 hB2 = relu2(u2h(auB.z) + db2);
            h2 hB3 = relu2(u2h(auB.w) + db3);
            float pA = fdot2(hA3, w3, fdot2(hA2, w2, fdot2(hA1, w1, fdot2(hA0, w0, 0.f))));
            float pB = fdot2(hB3, w3, fdot2(hB2, w2, fdot2(hB1, w1, fdot2(hB0, w0, 0.f))));

            // 16-lane DPP allreduce (both scalars, interleaved for ILP)
            tA = DPPADD(tA, 0xB1);  pA = DPPADD(pA, 0xB1);
            tB = DPPADD(tB, 0xB1);  pB = DPPADD(pB, 0xB1);
            tA = DPPADD(tA, 0x4E);  pA = DPPADD(pA, 0x4E);
            tB = DPPADD(tB, 0x4E);  pB = DPPADD(pB, 0x4E);
            tA = DPPADD(tA, 0x128); pA = DPPADD(pA, 0x128);
            tB = DPPADD(tB, 0x128); pB = DPPADD(pB, 0x128);
            tA = DPPADD(tA, 0x124); pA = DPPADD(pA, 0x124);
            tB = DPPADD(tB, 0x124); pB = DPPADD(pB, 0x124);

            float coefA = exp2f(tA * (pA + be2h) * KC);
            float coefB = hasB ? exp2f(tB * (pB + be2h) * KC) : 0.f;
            s_acc += coefA + coefB;

            float vA0, vA1, vB0, vB1;
            fp8x2_to_f32(uvA, vA0, vA1);
            fp8x2_to_f32(uvB, vB0, vB1);
            o0 = fmaf(coefA, vA0, fmaf(coefB, vB0, o0));
            o1 = fmaf(coefA, vA1, fmaf(coefB, vB1, o1));

            kuA = kuC; auA = auC; uvA = uvC;
            kuB = kuD; auB = auD; uvB = uvD;
            sna = s4a; snb = s4b;
        }
    }
    // write agg row (bf16, 256B) into first half of this node's qb row
    *(unsigned*)(qb_dst + (size_t)node * 512 + lane * 4) = f2bu(o0) | (f2bu(o1) << 16);
    if (i16 == 0) spart[node * 4 + myh] = s_acc;
}

// ---------------------------------------------------------------------------
// s_reduce: PARALLEL reduction of spart (NN*4) -> ssum[4] via atomics.
// ---------------------------------------------------------------------------
constexpr int SR_BLOCKS = 98;
__global__ __launch_bounds__(256) void s_reduce(const float* __restrict__ spart,
                                                float* __restrict__ ssum)
{
    int tid = blockIdx.x * 256 + threadIdx.x;
    int h = threadIdx.x & 3;
    float s = 0.f;
    for (int i = tid; i < NN * 4; i += SR_BLOCKS * 256) s += spart[i];
#pragma unroll
    for (int off = 4; off <= 32; off <<= 1) s += __shfl_xor(s, off);
    __shared__ float sm[4][4];
    int lane = threadIdx.x & 63, w = threadIdx.x >> 6;
    if (lane < 4) sm[w][h] = s;
    __syncthreads();
    if (threadIdx.x < 4) {
        float tot = sm[0][h] + sm[1][h] + sm[2][h] + sm[3][h];
        atomicAdd(&ssum[h], tot);
    }
}

// ---------------------------------------------------------------------------
// out_gemm: MFMA out GEMM + fused softmax-normalization + fused LN.
// Agg rows live at stride 512 B inside qb_dst (first half of each row).
// ---------------------------------------------------------------------------
__global__ __launch_bounds__(256) void out_gemm(
    const unsigned char* __restrict__ aggv, const bf16* __restrict__ WoT,
    const void* __restrict__ bo, const void* __restrict__ gamma,
    const void* __restrict__ beta, const unsigned* __restrict__ gw,
    const float* __restrict__ ssum,
    void* __restrict__ out)
{
    const bool f32 = (gw[0] == F32_ONE);
    int wave = threadIdx.x >> 6;
    int lane = threadIdx.x & 63;
    int quad = lane >> 4;
    int l16  = lane & 15;
    int rb = blockIdx.x * 64 + wave * 16;
    int m = rb + l16;
    int ma = (m < NN) ? m : 0;

    const bf16* arow = (const bf16*)(aggv + (size_t)ma * 512);
    short8 a[4];
#pragma unroll
    for (int h = 0; h < 4; ++h) {
        short8 raw = *(const short8*)(arow + h * 32 + quad * 8);
        float invh = 1.0f / ssum[h];
#pragma unroll
        for (int jj = 0; jj < 8; ++jj) {
            float f = __uint_as_float(((unsigned)(unsigned short)raw[jj]) << 16) * invh;
            raw[jj] = (short)f2bu(f);
        }
        a[h] = raw;
    }

    float o[8][4];
#pragma unroll
    for (int t = 0; t < 8; ++t) {
        const bf16* bp = WoT + (size_t)(t * 16 + l16) * OC + quad * 8;
        f32x4 acc = {0.f, 0.f, 0.f, 0.f};
#pragma unroll
        for (int h = 0; h < 4; ++h) {
            short8 bfr = *(const short8*)(bp + h * 32);
            acc = __builtin_amdgcn_mfma_f32_16x16x32_bf16(a[h], bfr, acc, 0, 0, 0);
        }
        float bias = ldf(bo, t * 16 + l16, f32);
#pragma unroll
        for (int r = 0; r < 4; ++r) o[t][r] = acc[r] + bias;
    }

#pragma unroll
    for (int r = 0; r < 4; ++r) {
        float s1 = 0.f, s2 = 0.f;
#pragma unroll
        for (int t = 0; t < 8; ++t) { s1 += o[t][r]; s2 += o[t][r] * o[t][r]; }
#pragma unroll
        for (int off = 1; off <= 8; off <<= 1) {
            s1 += __shfl_xor(s1, off);
            s2 += __shfl_xor(s2, off);
        }
        float mu = s1 * (1.0f / OC);
        float var = fmaxf(s2 * (1.0f / OC) - mu * mu, 0.f);
        float rs = rsqrtf(var + 1e-5f);
        int node = rb + quad * 4 + r;
        if (node < NN) {
#pragma unroll
            for (int t = 0; t < 8; ++t) {
                int col = t * 16 + l16;
                float y = (o[t][r] - mu) * rs * ldf(gamma, col, f32) + ldf(beta, col, f32);
                if (f32) ((float*)out)[(size_t)node * OC + col] = y;
                else     ((bf16*)out)[(size_t)node * OC + col] = __float2bfloat16(y);
            }
        }
    }
}

// ---------------------------------------------------------------------------
extern "C" void kernel_launch(void* const* d_in, const int* in_sizes, int n_in,
                              void* d_out, int out_size, void* d_ws, size_t ws_size,
                              hipStream_t stream)
{
    int p = 0;
    const void* x   = d_in[p++];
    const void* eia = d_in[p++];
    const void* eib = eia;
    int split = 0;
    if (n_in >= 17) { eib = d_in[p++]; split = 1; }
    const void* Wq   = d_in[p++];
    const void* bq   = d_in[p++];
    const void* Wk   = d_in[p++];
    const void* bk   = d_in[p++];
    const void* Wv   = d_in[p++];
    const void* bv   = d_in[p++];
    const void* We1  = d_in[p++];
    const void* be1  = d_in[p++];
    const void* We2  = d_in[p++];
    const void* be2  = d_in[p++];
    const void* Wo   = d_in[p++];
    const void* bo   = d_in[p++];
    const void* gamma= d_in[p++];
    const void* beta = d_in[p++];
    const unsigned* gw = (const unsigned*)gamma;

    // workspace layout (~72 MB). cnt and ssum adjacent -> single memset.
    char* w = (char*)d_ws;
    bf16*  xb     = (bf16*)w;                  w += (size_t)NN * IC * 2;  // 6.4 MB
    unsigned char* qb_dst = (unsigned char*)w; w += (size_t)NN * 512;     // 25.6 MB (f16 q|b')
    unsigned char* ka_src = (unsigned char*)w; w += (size_t)NN * 512;     // 25.6 MB (f16 k|a)
    unsigned char* vf8    = (unsigned char*)w; w += (size_t)NN * OC;      // 6.4 MB
    int*   ssrc   = (int*)w;                   w += (size_t)NE * 4;       // 3.2 MB
    int*   rank   = (int*)w;                   w += (size_t)NE * 4;       // 3.2 MB
    int*   cnt    = (int*)w;                   w += (size_t)NN * 4;       // 200 KB
    float* ssum   = (float*)w;                 w += 8 * 4;                // (memset w/ cnt)
    int*   rowptr = (int*)w;                   w += (size_t)(NN + 4) * 4; // padded to 16B
    int*   bsum   = (int*)w;                   w += 64 * 4;               // scan block sums
    float* spart  = (float*)w;                 w += (size_t)NN * 4 * 4;   // 800 KB
    unsigned* We2h = (unsigned*)w;             w += 256 * 4;              // 1 KB
    float* be2f   = (float*)w;                 w += NH * 4;
    bf16*  WcatT  = (bf16*)w;                  w += (size_t)5 * OC * IC * 2;
    float* bcat   = (float*)w;                 w += 5 * OC * 4;
    bf16*  WoT    = (bf16*)w;                  w += (size_t)OC * OC * 2;

    if (ws_size < (size_t)((char*)w - (char*)d_ws)) return;

    hipMemsetAsync(cnt, 0, (size_t)NN * 4 + 32, stream);   // cnt + ssum
    prep<<<PB_X + PB_W + PB_WO + PB_CNT + 1, 256, 0, stream>>>(
        x, Wq, bq, Wk, bk, Wv, bv, We1, be1, We2, be2, Wo, gw,
        eia, eib, split,
        xb, WcatT, WoT, cnt, rank, We2h, be2f, bcat);
    scan_part<<<SCAN_NB, 256, 0, stream>>>(cnt, bsum, rowptr);
    scan_fin<<<SCAN_NB, 256, 0, stream>>>(cnt, bsum, rowptr);
    node_gemm<<<NG_GEMM + NG_FILL, 256, 0, stream>>>(
        xb, WcatT, bcat, qb_dst, ka_src, vf8, eia, eib, split, rowptr, rank, ssrc);
    edge_gather<<<NN / 4, 256, 0, stream>>>(rowptr, ssrc, qb_dst, ka_src, vf8,
                                            We2h, be2f, spart);
    s_reduce<<<SR_BLOCKS, 256, 0, stream>>>(spart, ssum);
    out_gemm<<<(NN + 63) / 64, 256, 0, stream>>>(qb_dst, WoT, bo, gamma, beta, gw,
                                                 ssum, d_out);
}